// Round 3
// baseline (446.900 us; speedup 1.0000x reference)
//
#include <hip/hip_runtime.h>
#include <hip/hip_bf16.h>

#define D 64

typedef __attribute__((ext_vector_type(8))) short bf16x8;
typedef __attribute__((ext_vector_type(8))) unsigned short u16x8;
typedef __attribute__((ext_vector_type(4))) float f32x4;

__device__ __forceinline__ short f2bf(float x) {
    unsigned u = __float_as_uint(x);
    unsigned r = (u + 0x7fffu + ((u >> 16) & 1u)) >> 16;  // RNE
    return (short)r;
}
__device__ __forceinline__ float bf2f(unsigned short u) {
    return __uint_as_float((unsigned)u << 16);
}

// ---------------- int64-vs-int32 edge_index detection ----------------
__global__ void detect_kernel(const unsigned int* e32, int* flag) {
    __shared__ int nz;
    if (threadIdx.x == 0) nz = 0;
    __syncthreads();
    if (e32[2 * threadIdx.x + 1] != 0) nz = 1;
    __syncthreads();
    if (threadIdx.x == 0) *flag = (nz == 0) ? 1 : 0;
}

__device__ __forceinline__ int load_idx(const void* e, int is64, long long i) {
    if (is64) return (int)((const long long*)e)[i];
    return ((const int*)e)[i];
}

// ================= bucketed CSR build =================
#define NBLK 256   // blocks for count & scatter (pbh rows)
#define PADB 4096  // per-bucket slack in srcs2 (>= 15*256 pad + 15 align)

// ---- B1: per-block LDS bucket histogram -> global pbh[block][512] ----
__global__ __launch_bounds__(256) void bucket_count_kernel(
    const void* edges, const int* flag, int* pbh, int E, int shift) {
    __shared__ int h[512];
    for (int i = threadIdx.x; i < 512; i += 256) h[i] = 0;
    __syncthreads();
    int is64 = *flag;
    int chunk = (E + gridDim.x - 1) / gridDim.x;
    int s0 = blockIdx.x * chunk;
    int s1 = min(E, s0 + chunk);
    for (int e = s0 + (int)threadIdx.x; e < s1; e += 256) {
        int d = load_idx(edges, is64, (long long)E + e);
        atomicAdd(&h[d >> shift], 1);
    }
    __syncthreads();
    for (int i = threadIdx.x; i < 512; i += 256) pbh[blockIdx.x * 512 + i] = h[i];
}

// ---- B2a: per-bucket column scan ----
__global__ __launch_bounds__(256) void colscan_kernel(int* pbh, int* btot) {
    int b = blockIdx.x;  // bucket
    int k = threadIdx.x; // count-block
    __shared__ int sA[256], sB[256];
    int v = pbh[k * 512 + b];
    sA[k] = v;
    __syncthreads();
    int* src = sA;
    int* dst = sB;
    for (int d = 1; d < 256; d <<= 1) {
        dst[k] = src[k] + (k >= d ? src[k - d] : 0);
        __syncthreads();
        int* t = src; src = dst; dst = t;
    }
    pbh[k * 512 + b] = src[k] - v;  // exclusive prefix within column
    if (k == 255) btot[b] = src[255];
}

// ---- B2b: single-block scan of 512 bucket totals -> bbase ----
__global__ __launch_bounds__(512) void basescan_kernel(const int* btot, int* bbase, int E) {
    __shared__ int sA[512], sB[512];
    int b = threadIdx.x;
    int v = btot[b];
    sA[b] = v;
    __syncthreads();
    int* src = sA;
    int* dst = sB;
    for (int d = 1; d < 512; d <<= 1) {
        dst[b] = src[b] + (b >= d ? src[b - d] : 0);
        __syncthreads();
        int* t = src; src = dst; dst = t;
    }
    bbase[b] = src[b] - v;
    if (b == 0) bbase[512] = E;
}

// ---- B3: scatter edges into bucket-grouped staging ----
__global__ __launch_bounds__(256) void bucket_scatter_kernel(
    const void* edges, const int* flag, const int* pbh, const int* bbase,
    unsigned* staging, int E, int shift) {
    __shared__ int cur[512];
    for (int i = threadIdx.x; i < 512; i += 256)
        cur[i] = pbh[blockIdx.x * 512 + i] + bbase[i];
    __syncthreads();
    int is64 = *flag;
    int chunk = (E + gridDim.x - 1) / gridDim.x;
    int s0 = blockIdx.x * chunk;
    int s1 = min(E, s0 + chunk);
    unsigned mask = (unsigned)((1 << shift) - 1);
    for (int e = s0 + (int)threadIdx.x; e < s1; e += 256) {
        int s = load_idx(edges, is64, e);
        int d = load_idx(edges, is64, (long long)E + e);
        int b = d >> shift;
        int pos = atomicAdd(&cur[b], 1);  // LDS atomic
        staging[pos] = ((unsigned)s << shift) | ((unsigned)d & mask);
    }
}

// ---- B4: per-bucket counting sort -> PADDED srcs2 (byte offsets, sentinel) --
// Each node's edge slots are padded to a multiple of 16 with sentinel = zero
// row (row n of the message table), 16-aligned start. agg then needs no
// masks/tails: every batch is 16 unconditional gathers.
__global__ __launch_bounds__(256) void bucket_fill_kernel(
    const unsigned* __restrict__ staging, const int* __restrict__ bbase,
    int* __restrict__ pj0n, int* __restrict__ degv, float* __restrict__ dinv,
    int* __restrict__ srcs2, int shift, int n, int E) {
    int b = blockIdx.x;
    int bstart = bbase[b], bend = bbase[b + 1];
    int bsz = 1 << shift;
    unsigned mask = (unsigned)(bsz - 1);
    int v0 = b << shift;
    int nloc = min(bsz, n - v0);
    int Pb = ((bstart + 15) & ~15) + PADB * b;  // padded region base (16-aligned)
    int sentinel = n << 7;                       // byte offset of zero row

    __shared__ int cnt[512], cur[512], sA[512], sB[512];
    for (int i = threadIdx.x; i < bsz; i += 256) cnt[i] = 0;
    __syncthreads();
    for (int idx = bstart + (int)threadIdx.x; idx < bend; idx += 256)
        atomicAdd(&cnt[staging[idx] & mask], 1);
    __syncthreads();
    // scan padded counts pc = ceil(cnt/16)*16
    for (int i = threadIdx.x; i < bsz; i += 256) sA[i] = (cnt[i] + 15) & ~15;
    __syncthreads();
    int* src = sA;
    int* dst = sB;
    for (int d = 1; d < bsz; d <<= 1) {
        for (int i = threadIdx.x; i < bsz; i += 256)
            dst[i] = src[i] + (i >= d ? src[i - d] : 0);
        __syncthreads();
        int* t = src; src = dst; dst = t;
    }
    for (int i = threadIdx.x; i < bsz; i += 256) {
        int c = cnt[i];
        int pc = (c + 15) & ~15;
        int st = Pb + src[i] - pc;  // exclusive padded prefix, 16-aligned
        cur[i] = st;
        if (i < nloc) {
            pj0n[v0 + i] = st;
            degv[v0 + i] = c;
            dinv[v0 + i] = rsqrtf((float)(c + 1));
            for (int s2 = c; s2 < pc; s2++) srcs2[st + s2] = sentinel;
        }
    }
    __syncthreads();
    for (int idx = bstart + (int)threadIdx.x; idx < bend; idx += 256) {
        unsigned u = staging[idx];
        int ld = (int)(u & mask);
        int pos = atomicAdd(&cur[ld], 1);
        srcs2[pos] = (int)(u >> shift) << 7;  // pre-scaled byte offset
    }
}

// ================= batch-count-sorted node permutation (descending: LPT) ====
#define DBIN 256

__device__ __forceinline__ int deg_bin(int deg) {
    int nb = (deg + 15) >> 4;            // 16-edge batches
    return (DBIN - 1) - min(nb, DBIN - 1);  // descending nb -> ascending bin
}

__global__ __launch_bounds__(256) void deg_count_kernel(
    const int* __restrict__ degv, int* __restrict__ pdh, int n) {
    __shared__ int h[DBIN];
    for (int i = threadIdx.x; i < DBIN; i += 256) h[i] = 0;
    __syncthreads();
    int chunk = (n + gridDim.x - 1) / gridDim.x;
    int s0 = blockIdx.x * chunk;
    int s1 = min(n, s0 + chunk);
    for (int v = s0 + (int)threadIdx.x; v < s1; v += 256)
        atomicAdd(&h[deg_bin(degv[v])], 1);
    __syncthreads();
    for (int i = threadIdx.x; i < DBIN; i += 256) pdh[blockIdx.x * DBIN + i] = h[i];
}

__global__ __launch_bounds__(256) void deg_colscan_kernel(int* pdh, int* dtot) {
    int b = blockIdx.x;   // bin
    int k = threadIdx.x;  // count-block
    __shared__ int sA[256], sB[256];
    int v = pdh[k * DBIN + b];
    sA[k] = v;
    __syncthreads();
    int* src = sA;
    int* dst = sB;
    for (int d = 1; d < 256; d <<= 1) {
        dst[k] = src[k] + (k >= d ? src[k - d] : 0);
        __syncthreads();
        int* t = src; src = dst; dst = t;
    }
    pdh[k * DBIN + b] = src[k] - v;
    if (k == 255) dtot[b] = src[255];
}

__global__ __launch_bounds__(256) void deg_base_kernel(const int* dtot, int* dbase) {
    __shared__ int sA[256], sB[256];
    int b = threadIdx.x;
    int v = dtot[b];
    sA[b] = v;
    __syncthreads();
    int* src = sA;
    int* dst = sB;
    for (int d = 1; d < 256; d <<= 1) {
        dst[b] = src[b] + (b >= d ? src[b - d] : 0);
        __syncthreads();
        int* t = src; src = dst; dst = t;
    }
    dbase[b] = src[b] - v;
}

// scatter + pre-gather per-node metadata into sorted order
__global__ __launch_bounds__(256) void deg_scatter_kernel(
    const int* __restrict__ degv, const int* __restrict__ pj0n,
    const float* __restrict__ dinv,
    const int* __restrict__ pdh, const int* __restrict__ dbase,
    int* __restrict__ perm, int* __restrict__ pj0, int* __restrict__ pnb,
    float* __restrict__ pdinv, int n) {
    __shared__ int cur[DBIN];
    for (int i = threadIdx.x; i < DBIN; i += 256)
        cur[i] = pdh[blockIdx.x * DBIN + i] + dbase[i];
    __syncthreads();
    int chunk = (n + gridDim.x - 1) / gridDim.x;
    int s0 = blockIdx.x * chunk;
    int s1 = min(n, s0 + chunk);
    for (int v = s0 + (int)threadIdx.x; v < s1; v += 256) {
        int d = degv[v];
        int pos = atomicAdd(&cur[deg_bin(d)], 1);  // LDS atomic
        perm[pos] = v;
        pj0[pos] = pj0n[v];
        pnb[pos] = (d + 15) >> 4;
        pdinv[pos] = dinv[v];
    }
}

// ---------------- fused (BN+ReLU) -> [n,64]@[64,64] MFMA matmul ----------------
__global__ __launch_bounds__(256) void mm_bn_kernel(
    const float* __restrict__ Xf, const unsigned short* __restrict__ Xb, int x_is_bf16,
    const float* __restrict__ W,
    const float* __restrict__ stats, const float* __restrict__ gamma,
    const float* __restrict__ beta, int use_bn, float inv_n,
    const float* __restrict__ dinv,
    unsigned short* __restrict__ Y, int n) {
    int lane = threadIdx.x & 63;
    int m = lane & 15;
    int quad = lane >> 4;

    float sc[16], sh[16];
#pragma unroll
    for (int s = 0; s < 2; s++) {
#pragma unroll
        for (int j = 0; j < 8; j++) {
            float scale = 1.f, shift = 0.f;
            if (use_bn) {
                int f = s * 32 + quad * 8 + j;
                float mean = stats[f] * inv_n;
                float var = stats[64 + f] * inv_n - mean * mean;
                float rs = rsqrtf(var + 1e-5f);
                scale = rs * gamma[f];
                shift = beta[f] - mean * scale;
            }
            sc[s * 8 + j] = scale;
            sh[s * 8 + j] = shift;
        }
    }

    bf16x8 bfrag[4][2];
#pragma unroll
    for (int nt = 0; nt < 4; nt++) {
#pragma unroll
        for (int s = 0; s < 2; s++) {
#pragma unroll
            for (int j = 0; j < 8; j++) {
                int k = s * 32 + quad * 8 + j;
                bfrag[nt][s][j] = f2bf(W[k * 64 + nt * 16 + m]);
            }
        }
    }

    int wave = blockIdx.x * 4 + (threadIdx.x >> 6);
    int nwaves = gridDim.x * 4;
    int ntiles = (n + 15) >> 4;
    const f32x4 zero = {0.f, 0.f, 0.f, 0.f};

    for (int t = wave; t < ntiles; t += nwaves) {
        int r = t * 16 + m;
        if (r >= n) r = n - 1;  // redundant load; stores are guarded
        float av[16];
        if (x_is_bf16) {
            const unsigned short* xr = Xb + (long long)r * 64;
            u16x8 u0 = *(const u16x8*)(xr + quad * 8);
            u16x8 u1 = *(const u16x8*)(xr + 32 + quad * 8);
#pragma unroll
            for (int j = 0; j < 8; j++) {
                av[j] = bf2f(u0[j]);
                av[8 + j] = bf2f(u1[j]);
            }
        } else {
            const float* xr = Xf + (long long)r * 64;
            f32x4 a0 = *(const f32x4*)(xr + quad * 8);
            f32x4 a1 = *(const f32x4*)(xr + quad * 8 + 4);
            f32x4 a2 = *(const f32x4*)(xr + 32 + quad * 8);
            f32x4 a3 = *(const f32x4*)(xr + 32 + quad * 8 + 4);
#pragma unroll
            for (int j = 0; j < 4; j++) {
                av[j] = a0[j];
                av[4 + j] = a1[j];
                av[8 + j] = a2[j];
                av[12 + j] = a3[j];
            }
        }
        bf16x8 A0, A1;
#pragma unroll
        for (int j = 0; j < 8; j++) {
            float v0 = av[j] * sc[j] + sh[j];
            float v1 = av[8 + j] * sc[8 + j] + sh[8 + j];
            if (use_bn) {
                v0 = fmaxf(v0, 0.f);
                v1 = fmaxf(v1, 0.f);
            }
            A0[j] = f2bf(v0);
            A1[j] = f2bf(v1);
        }

        f32x4 acc[4];
#pragma unroll
        for (int nt = 0; nt < 4; nt++) {
            acc[nt] = __builtin_amdgcn_mfma_f32_16x16x32_bf16(A0, bfrag[nt][0], zero, 0, 0, 0);
            acc[nt] = __builtin_amdgcn_mfma_f32_16x16x32_bf16(A1, bfrag[nt][1], acc[nt], 0, 0, 0);
        }

        int row0 = t * 16 + quad * 4;
        float dv[4];
#pragma unroll
        for (int i = 0; i < 4; i++) {
            int rr = row0 + i;
            dv[i] = (rr < n) ? dinv[rr] : 0.f;
        }
#pragma unroll
        for (int nt = 0; nt < 4; nt++) {
#pragma unroll
            for (int i = 0; i < 4; i++) {
                int rr = row0 + i;
                if (rr < n)
                    Y[(long long)rr * 64 + nt * 16 + m] = (unsigned short)f2bf(acc[nt][i] * dv[i]);
            }
        }
    }
}

// ---------------- aggregation v6: maskless 16-deep gather batches ------------
// Wave = 8 subgroups x 8 lanes; one group of 8 equal-work nodes per wave
// (perm sorted by batch count, DESCENDING -> LPT backfill). Inner loop:
// 4 x int4 index loads + 16 unconditional dwordx4 row gathers (indices are
// pre-scaled byte offsets; pad slots hit the zero row at row n). 16 gathers
// in flight per wave; 12500 waves.
__global__ __launch_bounds__(256) void agg_kernel(
    const unsigned short* __restrict__ T,
    const int* __restrict__ perm,
    const int* __restrict__ pj0,
    const int* __restrict__ pnb,
    const float* __restrict__ pdinv,
    const int* __restrict__ srcs2,
    const float* __restrict__ bias,
    unsigned short* __restrict__ out16,
    float* __restrict__ out32, int out_bf16,
    float* __restrict__ stats, int do_stats,
    int n) {
    __shared__ float S[128];  // [0:64)=sum, [64:128)=sumsq
    if (do_stats) {
        if (threadIdx.x < 128) S[threadIdx.x] = 0.f;
        __syncthreads();
    }
    int lane = threadIdx.x & 63;
    int sub = lane >> 3;  // node slot 0..7
    int c = lane & 7;     // feature group: features 8c..8c+7
    int wave = blockIdx.x * 4 + (threadIdx.x >> 6);
    int nwaves = gridDim.x * 4;
    int ngrp = (n + 7) >> 3;
    f32x4 bi0 = *(const f32x4*)(bias + c * 8);
    f32x4 bi1 = *(const f32x4*)(bias + c * 8 + 4);

    const char* Tb = (const char*)T;
    unsigned coff = (unsigned)c << 4;  // c*16 bytes within a 128B row

    for (int g = wave; g < ngrp; g += nwaves) {
        int i = g * 8 + sub;
        int valid = i < n;
        int ic = valid ? i : n - 1;
        int v = perm[ic];
        int j = pj0[ic];
        int nb = pnb[ic];
        float dv = pdinv[ic];
        // self loop (pre-scaled message row)
        u16x8 sv = *(const u16x8*)(Tb + (((unsigned)v << 7) + coff));
        float acc[8];
#pragma unroll
        for (int q = 0; q < 8; q++) acc[q] = bf2f(sv[q]);

        for (int bb = 0; bb < nb; bb++) {
            const int* sp = srcs2 + j;
            int4 s0 = *(const int4*)sp;
            int4 s1 = *(const int4*)(sp + 4);
            int4 s2 = *(const int4*)(sp + 8);
            int4 s3 = *(const int4*)(sp + 12);
            u16x8 r[16];
            r[0]  = *(const u16x8*)(Tb + ((unsigned)s0.x + coff));
            r[1]  = *(const u16x8*)(Tb + ((unsigned)s0.y + coff));
            r[2]  = *(const u16x8*)(Tb + ((unsigned)s0.z + coff));
            r[3]  = *(const u16x8*)(Tb + ((unsigned)s0.w + coff));
            r[4]  = *(const u16x8*)(Tb + ((unsigned)s1.x + coff));
            r[5]  = *(const u16x8*)(Tb + ((unsigned)s1.y + coff));
            r[6]  = *(const u16x8*)(Tb + ((unsigned)s1.z + coff));
            r[7]  = *(const u16x8*)(Tb + ((unsigned)s1.w + coff));
            r[8]  = *(const u16x8*)(Tb + ((unsigned)s2.x + coff));
            r[9]  = *(const u16x8*)(Tb + ((unsigned)s2.y + coff));
            r[10] = *(const u16x8*)(Tb + ((unsigned)s2.z + coff));
            r[11] = *(const u16x8*)(Tb + ((unsigned)s2.w + coff));
            r[12] = *(const u16x8*)(Tb + ((unsigned)s3.x + coff));
            r[13] = *(const u16x8*)(Tb + ((unsigned)s3.y + coff));
            r[14] = *(const u16x8*)(Tb + ((unsigned)s3.z + coff));
            r[15] = *(const u16x8*)(Tb + ((unsigned)s3.w + coff));
#pragma unroll
            for (int u = 0; u < 16; u++) {
#pragma unroll
                for (int q = 0; q < 8; q++) acc[q] += bf2f(r[u][q]);
            }
            j += 16;
        }

        float val[8];
#pragma unroll
        for (int q = 0; q < 4; q++) {
            val[q] = dv * acc[q] + bi0[q];
            val[4 + q] = dv * acc[4 + q] + bi1[q];
        }
        if (valid) {
            if (out_bf16) {
                u16x8 o;
#pragma unroll
                for (int q = 0; q < 8; q++) o[q] = (unsigned short)f2bf(val[q]);
                *(u16x8*)((char*)out16 + (((unsigned)v << 7) + coff)) = o;
            } else {
                f32x4 o0 = {val[0], val[1], val[2], val[3]};
                f32x4 o1 = {val[4], val[5], val[6], val[7]};
                float* op = out32 + (((unsigned)v << 6) + ((unsigned)c << 3));
                *(f32x4*)op = o0;
                *(f32x4*)(op + 4) = o1;
            }
            if (do_stats) {
#pragma unroll
                for (int q = 0; q < 8; q++) {
                    atomicAdd(&S[c * 8 + q], val[q]);
                    atomicAdd(&S[64 + c * 8 + q], val[q] * val[q]);
                }
            }
        }
    }
    if (do_stats) {
        __syncthreads();
        if (threadIdx.x < 128) atomicAdd(&stats[threadIdx.x], S[threadIdx.x]);
    }
}

// ---------------- host ----------------
extern "C" void kernel_launch(void* const* d_in, const int* in_sizes, int n_in,
                              void* d_out, int out_size, void* d_ws, size_t ws_size,
                              hipStream_t stream) {
    const float* x = (const float*)d_in[0];
    const void* edges = d_in[1];
    const float* W1 = (const float*)d_in[3];
    const float* b1 = (const float*)d_in[4];
    const float* gamma1 = (const float*)d_in[5];
    const float* beta1 = (const float*)d_in[6];
    const float* W2 = (const float*)d_in[7];
    const float* b2 = (const float*)d_in[8];
    const float* gamma2 = (const float*)d_in[9];
    const float* beta2 = (const float*)d_in[10];
    const float* W3 = (const float*)d_in[11];
    const float* b3 = (const float*)d_in[12];

    const int N = in_sizes[0] / D;
    const int E = in_sizes[1] / 2;
    const float inv_n = 1.f / (float)N;

    int shift = 8;
    while ((((long long)N - 1) >> shift) + 1 > 512) shift++;
    const int nbuk = (int)(((long long)N - 1) >> shift) + 1;

    char* ws = (char*)d_ws;
    size_t off = 0;
    auto alloc = [&](size_t bytes) -> void* {
        void* p = ws + off;
        off = (off + bytes + 255) & ~(size_t)255;
        return p;
    };
    float*    dinv    = (float*)   alloc((size_t)N * 4);
    int*      pj0n    = (int*)     alloc((size_t)N * 4);
    int*      degv    = (int*)     alloc((size_t)N * 4);
    int*      srcs2   = (int*)     alloc(((size_t)E + (size_t)PADB * 512 + 64) * 4);
    unsigned* staging = (unsigned*)alloc((size_t)E * 4);
    int*      pbh     = (int*)     alloc((size_t)NBLK * 512 * 4);
    int*      btot    = (int*)     alloc(512 * 4);
    int*      bbase   = (int*)     alloc(513 * 4);
    int*      flag    = (int*)     alloc(4);
    float*    stats   = (float*)   alloc(256 * 4);  // [0:128)=layer1, [128:256)=layer2
    int*      pdh     = (int*)     alloc((size_t)NBLK * DBIN * 4);
    int*      dtot    = (int*)     alloc(DBIN * 4);
    int*      dbase   = (int*)     alloc(DBIN * 4);
    int*      perm    = (int*)     alloc((size_t)N * 4);
    int*      pj0v    = (int*)     alloc((size_t)N * 4);
    int*      pnbv    = (int*)     alloc((size_t)N * 4);
    float*    pdinv   = (float*)   alloc((size_t)N * 4);
    unsigned short* bufA = (unsigned short*)alloc((size_t)(N + 1) * D * 2);  // + zero row
    unsigned short* hbuf = (unsigned short*)alloc((size_t)N * D * 2);
    float*    outf    = (float*)d_out;  // final fp32 output

    const int ngrp = (N + 7) >> 3;
    const int AGGB = (ngrp + 3) / 4;  // one group per wave
    const int MMB  = 782;             // 6250 tiles / (782*4 waves) = 2 tiles/wave

    // ---- bucketed CSR build (padded srcs2, byte offsets, zero-row sentinel) ----
    detect_kernel<<<1, 256, 0, stream>>>((const unsigned int*)edges, flag);
    bucket_count_kernel<<<NBLK, 256, 0, stream>>>(edges, flag, pbh, E, shift);
    colscan_kernel<<<512, 256, 0, stream>>>(pbh, btot);
    basescan_kernel<<<1, 512, 0, stream>>>(btot, bbase, E);
    bucket_scatter_kernel<<<NBLK, 256, 0, stream>>>(edges, flag, pbh, bbase, staging, E, shift);
    bucket_fill_kernel<<<nbuk, 256, 0, stream>>>(staging, bbase, pj0n, degv, dinv, srcs2,
                                                 shift, N, E);
    // ---- batch-count sort, descending (LPT) ----
    deg_count_kernel<<<NBLK, 256, 0, stream>>>(degv, pdh, N);
    deg_colscan_kernel<<<DBIN, 256, 0, stream>>>(pdh, dtot);
    deg_base_kernel<<<1, 256, 0, stream>>>(dtot, dbase);
    deg_scatter_kernel<<<NBLK, 256, 0, stream>>>(degv, pj0n, dinv, pdh, dbase,
                                                 perm, pj0v, pnbv, pdinv, N);
    hipMemsetAsync(stats, 0, 256 * 4, stream);
    hipMemsetAsync(bufA + (size_t)N * D, 0, D * 2, stream);  // zero row (gather sink)

    // ---- layer 1 (x fp32 in; agg fuses BN1 stats) ----
    mm_bn_kernel<<<MMB, 256, 0, stream>>>(x, nullptr, 0, W1, nullptr, nullptr, nullptr, 0,
                                          inv_n, dinv, bufA, N);
    agg_kernel<<<AGGB, 256, 0, stream>>>(bufA, perm, pj0v, pnbv, pdinv, srcs2, b1,
                                         hbuf, nullptr, 1, stats, 1, N);

    // ---- layer 2 (hbuf bf16 in; BN1+ReLU fused in mm; agg fuses BN2 stats) ----
    mm_bn_kernel<<<MMB, 256, 0, stream>>>(nullptr, hbuf, 1, W2, stats, gamma1, beta1, 1,
                                          inv_n, dinv, bufA, N);
    agg_kernel<<<AGGB, 256, 0, stream>>>(bufA, perm, pj0v, pnbv, pdinv, srcs2, b2,
                                         hbuf, nullptr, 1, stats + 128, 1, N);

    // ---- layer 3 (hbuf bf16 in; BN2+ReLU fused; fp32 out to d_out) ----
    mm_bn_kernel<<<MMB, 256, 0, stream>>>(nullptr, hbuf, 1, W3, stats + 128, gamma2, beta2, 1,
                                          inv_n, dinv, bufA, N);
    agg_kernel<<<AGGB, 256, 0, stream>>>(bufA, perm, pj0v, pnbv, pdinv, srcs2, b3,
                                         nullptr, outf, 0, nullptr, 0, N);
}

// Round 4
// 320.778 us; speedup vs baseline: 1.3932x; 1.3932x over previous
//
#include <hip/hip_runtime.h>
#include <hip/hip_bf16.h>

#define D 64

typedef __attribute__((ext_vector_type(8))) short bf16x8;
typedef __attribute__((ext_vector_type(8))) unsigned short u16x8;
typedef __attribute__((ext_vector_type(4))) float f32x4;

__device__ __forceinline__ short f2bf(float x) {
    unsigned u = __float_as_uint(x);
    unsigned r = (u + 0x7fffu + ((u >> 16) & 1u)) >> 16;  // RNE
    return (short)r;
}
__device__ __forceinline__ float bf2f(unsigned short u) {
    return __uint_as_float((unsigned)u << 16);
}

// ---------------- int64-vs-int32 edge_index detection ----------------
__global__ void detect_kernel(const unsigned int* e32, int* flag) {
    __shared__ int nz;
    if (threadIdx.x == 0) nz = 0;
    __syncthreads();
    if (e32[2 * threadIdx.x + 1] != 0) nz = 1;
    __syncthreads();
    if (threadIdx.x == 0) *flag = (nz == 0) ? 1 : 0;
}

__device__ __forceinline__ int load_idx(const void* e, int is64, long long i) {
    if (is64) return (int)((const long long*)e)[i];
    return ((const int*)e)[i];
}

// ================= bucketed CSR build (r0-proven) =================
#define NBLK 256  // blocks for count & scatter (pbh rows)

// ---- B1: per-block LDS bucket histogram -> global pbh[block][512] ----
__global__ __launch_bounds__(256) void bucket_count_kernel(
    const void* edges, const int* flag, int* pbh, int E, int shift) {
    __shared__ int h[512];
    for (int i = threadIdx.x; i < 512; i += 256) h[i] = 0;
    __syncthreads();
    int is64 = *flag;
    int chunk = (E + gridDim.x - 1) / gridDim.x;
    int s0 = blockIdx.x * chunk;
    int s1 = min(E, s0 + chunk);
    for (int e = s0 + (int)threadIdx.x; e < s1; e += 256) {
        int d = load_idx(edges, is64, (long long)E + e);
        atomicAdd(&h[d >> shift], 1);
    }
    __syncthreads();
    for (int i = threadIdx.x; i < 512; i += 256) pbh[blockIdx.x * 512 + i] = h[i];
}

// ---- B2a: per-bucket column scan ----
__global__ __launch_bounds__(256) void colscan_kernel(int* pbh, int* btot) {
    int b = blockIdx.x;  // bucket
    int k = threadIdx.x; // count-block
    __shared__ int sA[256], sB[256];
    int v = pbh[k * 512 + b];
    sA[k] = v;
    __syncthreads();
    int* src = sA;
    int* dst = sB;
    for (int d = 1; d < 256; d <<= 1) {
        dst[k] = src[k] + (k >= d ? src[k - d] : 0);
        __syncthreads();
        int* t = src; src = dst; dst = t;
    }
    pbh[k * 512 + b] = src[k] - v;  // exclusive prefix within column
    if (k == 255) btot[b] = src[255];
}

// ---- B2b: single-block scan of 512 bucket totals -> bbase ----
__global__ __launch_bounds__(512) void basescan_kernel(const int* btot, int* bbase, int E) {
    __shared__ int sA[512], sB[512];
    int b = threadIdx.x;
    int v = btot[b];
    sA[b] = v;
    __syncthreads();
    int* src = sA;
    int* dst = sB;
    for (int d = 1; d < 512; d <<= 1) {
        dst[b] = src[b] + (b >= d ? src[b - d] : 0);
        __syncthreads();
        int* t = src; src = dst; dst = t;
    }
    bbase[b] = src[b] - v;
    if (b == 0) bbase[512] = E;
}

// ---- B3: scatter, single edge pass, LDS cursors = pbh prefix + bbase ----
__global__ __launch_bounds__(256) void bucket_scatter_kernel(
    const void* edges, const int* flag, const int* pbh, const int* bbase,
    unsigned* staging, int E, int shift) {
    __shared__ int cur[512];
    for (int i = threadIdx.x; i < 512; i += 256)
        cur[i] = pbh[blockIdx.x * 512 + i] + bbase[i];
    __syncthreads();
    int is64 = *flag;
    int chunk = (E + gridDim.x - 1) / gridDim.x;
    int s0 = blockIdx.x * chunk;
    int s1 = min(E, s0 + chunk);
    unsigned mask = (unsigned)((1 << shift) - 1);
    for (int e = s0 + (int)threadIdx.x; e < s1; e += 256) {
        int s = load_idx(edges, is64, e);
        int d = load_idx(edges, is64, (long long)E + e);
        int b = d >> shift;
        int pos = atomicAdd(&cur[b], 1);  // LDS atomic
        staging[pos] = ((unsigned)s << shift) | ((unsigned)d & mask);
    }
}

// ---- B4: one block per bucket: LDS counting sort by local dst ----
__global__ __launch_bounds__(256) void bucket_fill_kernel(
    const unsigned* __restrict__ staging, const int* __restrict__ bbase,
    int* __restrict__ offs, float* __restrict__ dinv, int* __restrict__ srcs,
    int shift, int n, int E) {
    int b = blockIdx.x;
    int bstart = bbase[b], bend = bbase[b + 1];
    int bsz = 1 << shift;
    unsigned mask = (unsigned)(bsz - 1);
    int v0 = b << shift;
    int nloc = min(bsz, n - v0);

    __shared__ int cnt[512], cur[512], sA[512], sB[512];
    for (int i = threadIdx.x; i < bsz; i += 256) cnt[i] = 0;
    __syncthreads();
    for (int idx = bstart + (int)threadIdx.x; idx < bend; idx += 256)
        atomicAdd(&cnt[staging[idx] & mask], 1);
    __syncthreads();
    for (int i = threadIdx.x; i < bsz; i += 256) sA[i] = cnt[i];
    __syncthreads();
    int* src = sA;
    int* dst = sB;
    for (int d = 1; d < bsz; d <<= 1) {
        for (int i = threadIdx.x; i < bsz; i += 256)
            dst[i] = src[i] + (i >= d ? src[i - d] : 0);
        __syncthreads();
        int* t = src; src = dst; dst = t;
    }
    for (int i = threadIdx.x; i < bsz; i += 256) {
        int excl = src[i] - cnt[i];
        cur[i] = excl;
        if (i < nloc) {
            offs[v0 + i] = bstart + excl;
            dinv[v0 + i] = rsqrtf((float)(cnt[i] + 1));
        }
    }
    if (b == 0 && threadIdx.x == 0) offs[n] = E;
    __syncthreads();
    for (int idx = bstart + (int)threadIdx.x; idx < bend; idx += 256) {
        unsigned u = staging[idx];
        int ld = (int)(u & mask);
        int pos = atomicAdd(&cur[ld], 1);
        srcs[bstart + pos] = (int)(u >> shift);
    }
}

// ---------------- fused (BN+ReLU) -> [n,64]@[64,64] MFMA matmul ----------------
__global__ __launch_bounds__(256) void mm_bn_kernel(
    const float* __restrict__ Xf, const unsigned short* __restrict__ Xb, int x_is_bf16,
    const float* __restrict__ W,
    const float* __restrict__ stats, const float* __restrict__ gamma,
    const float* __restrict__ beta, int use_bn, float inv_n,
    const float* __restrict__ dinv,
    unsigned short* __restrict__ Y, int n) {
    int lane = threadIdx.x & 63;
    int m = lane & 15;
    int quad = lane >> 4;

    float sc[16], sh[16];
#pragma unroll
    for (int s = 0; s < 2; s++) {
#pragma unroll
        for (int j = 0; j < 8; j++) {
            float scale = 1.f, shift = 0.f;
            if (use_bn) {
                int f = s * 32 + quad * 8 + j;
                float mean = stats[f] * inv_n;
                float var = stats[64 + f] * inv_n - mean * mean;
                float rs = rsqrtf(var + 1e-5f);
                scale = rs * gamma[f];
                shift = beta[f] - mean * scale;
            }
            sc[s * 8 + j] = scale;
            sh[s * 8 + j] = shift;
        }
    }

    bf16x8 bfrag[4][2];
#pragma unroll
    for (int nt = 0; nt < 4; nt++) {
#pragma unroll
        for (int s = 0; s < 2; s++) {
#pragma unroll
            for (int j = 0; j < 8; j++) {
                int k = s * 32 + quad * 8 + j;
                bfrag[nt][s][j] = f2bf(W[k * 64 + nt * 16 + m]);
            }
        }
    }

    int wave = blockIdx.x * 4 + (threadIdx.x >> 6);
    int nwaves = gridDim.x * 4;
    int ntiles = (n + 15) >> 4;
    const f32x4 zero = {0.f, 0.f, 0.f, 0.f};

    for (int t = wave; t < ntiles; t += nwaves) {
        int r = t * 16 + m;
        if (r >= n) r = n - 1;  // redundant load; stores are guarded
        float av[16];
        if (x_is_bf16) {
            const unsigned short* xr = Xb + (long long)r * 64;
            u16x8 u0 = *(const u16x8*)(xr + quad * 8);
            u16x8 u1 = *(const u16x8*)(xr + 32 + quad * 8);
#pragma unroll
            for (int j = 0; j < 8; j++) {
                av[j] = bf2f(u0[j]);
                av[8 + j] = bf2f(u1[j]);
            }
        } else {
            const float* xr = Xf + (long long)r * 64;
            f32x4 a0 = *(const f32x4*)(xr + quad * 8);
            f32x4 a1 = *(const f32x4*)(xr + quad * 8 + 4);
            f32x4 a2 = *(const f32x4*)(xr + 32 + quad * 8);
            f32x4 a3 = *(const f32x4*)(xr + 32 + quad * 8 + 4);
#pragma unroll
            for (int j = 0; j < 4; j++) {
                av[j] = a0[j];
                av[4 + j] = a1[j];
                av[8 + j] = a2[j];
                av[12 + j] = a3[j];
            }
        }
        bf16x8 A0, A1;
#pragma unroll
        for (int j = 0; j < 8; j++) {
            float v0 = av[j] * sc[j] + sh[j];
            float v1 = av[8 + j] * sc[8 + j] + sh[8 + j];
            if (use_bn) {
                v0 = fmaxf(v0, 0.f);
                v1 = fmaxf(v1, 0.f);
            }
            A0[j] = f2bf(v0);
            A1[j] = f2bf(v1);
        }

        f32x4 acc[4];
#pragma unroll
        for (int nt = 0; nt < 4; nt++) {
            acc[nt] = __builtin_amdgcn_mfma_f32_16x16x32_bf16(A0, bfrag[nt][0], zero, 0, 0, 0);
            acc[nt] = __builtin_amdgcn_mfma_f32_16x16x32_bf16(A1, bfrag[nt][1], acc[nt], 0, 0, 0);
        }

        int row0 = t * 16 + quad * 4;
        float dv[4];
#pragma unroll
        for (int i = 0; i < 4; i++) {
            int rr = row0 + i;
            dv[i] = (rr < n) ? dinv[rr] : 0.f;
        }
#pragma unroll
        for (int nt = 0; nt < 4; nt++) {
#pragma unroll
            for (int i = 0; i < 4; i++) {
                int rr = row0 + i;
                if (rr < n)
                    Y[(long long)rr * 64 + nt * 16 + m] = (unsigned short)f2bf(acc[nt][i] * dv[i]);
            }
        }
    }
}

// ---------------- aggregation (r0-proven geometry + micro-opts) --------------
// One wave per dst node, lane = feature (each gather inst = one full 128B row
// across 64 lanes). 25000 blocks -> ~max wave residency (the empirically
// dominant factor for this latency-bound kernel). Micro-opts vs r0:
//  - 32-bit byte-offset addressing (no 64-bit mul chains)
//  - readfirstlane on offs -> srcs index loads scalarize (s_load)
//  - BN sum/sumsq fused: block LDS reduce -> 16-slab global atomics
//    (contention/address = 25000/16 = 1562, the level r1 proved safe)
__global__ __launch_bounds__(256) void agg_kernel(const unsigned short* __restrict__ T,
                                                  const int* __restrict__ offs,
                                                  const int* __restrict__ srcs,
                                                  const float* __restrict__ dinv,
                                                  const float* __restrict__ bias,
                                                  unsigned short* __restrict__ out16,
                                                  float* __restrict__ out32, int out_bf16,
                                                  float* __restrict__ slabs, int do_stats,
                                                  int n) {
    int v = blockIdx.x * 4 + (threadIdx.x >> 6);
    int lane = threadIdx.x & 63;
    int valid = v < n;
    int vc = valid ? v : n - 1;
    float val;
    {
        float acc = bf2f(T[((unsigned)vc << 6) + lane]);  // self-loop (pre-scaled)
        int j0 = __builtin_amdgcn_readfirstlane(offs[vc]);
        int j1 = __builtin_amdgcn_readfirstlane(offs[vc + 1]);
        int j = j0;
        for (; j + 8 <= j1; j += 8) {
            int sidx[8];
#pragma unroll
            for (int u = 0; u < 8; u++) sidx[u] = srcs[j + u];  // scalar loads
            float t[8];
#pragma unroll
            for (int u = 0; u < 8; u++)
                t[u] = bf2f(T[((unsigned)sidx[u] << 6) + lane]);
            acc += ((t[0] + t[1]) + (t[2] + t[3])) + ((t[4] + t[5]) + (t[6] + t[7]));
        }
        if (j < j1) {  // single masked tail batch
            int sidx[8];
            float wgt[8];
#pragma unroll
            for (int u = 0; u < 8; u++) {
                int jj = j + u;
                int jc = jj < j1 ? jj : j1 - 1;
                sidx[u] = srcs[jc];
                wgt[u] = (jj < j1) ? 1.f : 0.f;
            }
            float t[8];
#pragma unroll
            for (int u = 0; u < 8; u++)
                t[u] = bf2f(T[((unsigned)sidx[u] << 6) + lane]);
            float p0 = wgt[0] * t[0] + wgt[1] * t[1];
            float p1 = wgt[2] * t[2] + wgt[3] * t[3];
            float p2 = wgt[4] * t[4] + wgt[5] * t[5];
            float p3 = wgt[6] * t[6] + wgt[7] * t[7];
            acc += (p0 + p1) + (p2 + p3);
        }
        val = dinv[vc] * acc + bias[lane];
        if (valid) {
            if (out_bf16)
                out16[((unsigned)v << 6) + lane] = (unsigned short)f2bf(val);
            else
                out32[((unsigned)v << 6) + lane] = val;
        }
    }
    if (do_stats) {
        __shared__ float ls[256], lq[256];
        float x = valid ? val : 0.f;
        ls[threadIdx.x] = x;
        lq[threadIdx.x] = x * x;
        __syncthreads();
        int tid = threadIdx.x;
        if (tid < 128) {
            int f = tid & 63;
            const float* a = (tid < 64) ? ls : lq;
            float r = a[f] + a[64 + f] + a[128 + f] + a[192 + f];
            // slab row layout: [sum(64) | sumsq(64)]; tid encodes both halves
            atomicAdd(&slabs[((unsigned)(blockIdx.x & 15)) * 128 + tid], r);
        }
    }
}

// ---------------- collapse 16 stat slabs -> canonical 128 floats -------------
__global__ __launch_bounds__(128) void redstats_kernel(const float* __restrict__ slabs,
                                                       float* __restrict__ out) {
    int t = threadIdx.x;
    float s = 0.f;
#pragma unroll
    for (int k = 0; k < 16; k++) s += slabs[k * 128 + t];
    out[t] = s;
}

// ---------------- host ----------------
extern "C" void kernel_launch(void* const* d_in, const int* in_sizes, int n_in,
                              void* d_out, int out_size, void* d_ws, size_t ws_size,
                              hipStream_t stream) {
    const float* x = (const float*)d_in[0];
    const void* edges = d_in[1];
    const float* W1 = (const float*)d_in[3];
    const float* b1 = (const float*)d_in[4];
    const float* gamma1 = (const float*)d_in[5];
    const float* beta1 = (const float*)d_in[6];
    const float* W2 = (const float*)d_in[7];
    const float* b2 = (const float*)d_in[8];
    const float* gamma2 = (const float*)d_in[9];
    const float* beta2 = (const float*)d_in[10];
    const float* W3 = (const float*)d_in[11];
    const float* b3 = (const float*)d_in[12];

    const int N = in_sizes[0] / D;
    const int E = in_sizes[1] / 2;
    const float inv_n = 1.f / (float)N;

    int shift = 8;
    while ((((long long)N - 1) >> shift) + 1 > 512) shift++;
    const int nbuk = (int)(((long long)N - 1) >> shift) + 1;

    char* ws = (char*)d_ws;
    size_t off = 0;
    auto alloc = [&](size_t bytes) -> void* {
        void* p = ws + off;
        off = (off + bytes + 255) & ~(size_t)255;
        return p;
    };
    float*    dinv    = (float*)   alloc((size_t)N * 4);
    int*      offs    = (int*)     alloc((size_t)(N + 1) * 4);
    int*      srcs    = (int*)     alloc((size_t)E * 4);
    unsigned* staging = (unsigned*)alloc((size_t)E * 4);
    int*      pbh     = (int*)     alloc((size_t)NBLK * 512 * 4);
    int*      btot    = (int*)     alloc(512 * 4);
    int*      bbase   = (int*)     alloc(513 * 4);
    int*      flag    = (int*)     alloc(4);
    float*    slabs   = (float*)   alloc((size_t)2 * 16 * 128 * 4);  // L1 | L2 slab regions
    float*    canon   = (float*)   alloc(256 * 4);                   // canonical stats
    unsigned short* bufA = (unsigned short*)alloc((size_t)N * D * 2);  // bf16 messages
    unsigned short* hbuf = (unsigned short*)alloc((size_t)N * D * 2);  // bf16 node feats
    float*    outf    = (float*)d_out;  // final fp32 output

    const int AGGB = (N + 3) / 4;  // one wave per node (r0-proven residency)
    const int MMB  = 782;          // 6250 tiles / (782*4 waves) = 2 tiles/wave

    // ---- bucketed CSR build (once, reused 3x; zero global atomics) ----
    detect_kernel<<<1, 256, 0, stream>>>((const unsigned int*)edges, flag);
    bucket_count_kernel<<<NBLK, 256, 0, stream>>>(edges, flag, pbh, E, shift);
    colscan_kernel<<<512, 256, 0, stream>>>(pbh, btot);
    basescan_kernel<<<1, 512, 0, stream>>>(btot, bbase, E);
    bucket_scatter_kernel<<<NBLK, 256, 0, stream>>>(edges, flag, pbh, bbase, staging, E, shift);
    bucket_fill_kernel<<<nbuk, 256, 0, stream>>>(staging, bbase, offs, dinv, srcs, shift, N, E);
    hipMemsetAsync(slabs, 0, (size_t)2 * 16 * 128 * 4, stream);

    // ---- layer 1 (x fp32 in; agg fuses BN1 stats) ----
    mm_bn_kernel<<<MMB, 256, 0, stream>>>(x, nullptr, 0, W1, nullptr, nullptr, nullptr, 0,
                                          inv_n, dinv, bufA, N);
    agg_kernel<<<AGGB, 256, 0, stream>>>(bufA, offs, srcs, dinv, b1, hbuf, nullptr, 1,
                                         slabs, 1, N);
    redstats_kernel<<<1, 128, 0, stream>>>(slabs, canon);

    // ---- layer 2 (hbuf bf16 in; BN1+ReLU fused in mm; agg fuses BN2 stats) ----
    mm_bn_kernel<<<MMB, 256, 0, stream>>>(nullptr, hbuf, 1, W2, canon, gamma1, beta1, 1,
                                          inv_n, dinv, bufA, N);
    agg_kernel<<<AGGB, 256, 0, stream>>>(bufA, offs, srcs, dinv, b2, hbuf, nullptr, 1,
                                         slabs + 16 * 128, 1, N);
    redstats_kernel<<<1, 128, 0, stream>>>(slabs + 16 * 128, canon + 128);

    // ---- layer 3 (hbuf bf16 in; BN2+ReLU fused; fp32 out to d_out) ----
    mm_bn_kernel<<<MMB, 256, 0, stream>>>(nullptr, hbuf, 1, W3, canon + 128, gamma2, beta2, 1,
                                          inv_n, dinv, bufA, N);
    agg_kernel<<<AGGB, 256, 0, stream>>>(bufA, offs, srcs, dinv, b3, nullptr, outf, 0,
                                         nullptr, 0, N);
}

// Round 5
// 306.580 us; speedup vs baseline: 1.4577x; 1.0463x over previous
//
#include <hip/hip_runtime.h>
#include <hip/hip_bf16.h>

#define D 64

typedef __attribute__((ext_vector_type(8))) short bf16x8;
typedef __attribute__((ext_vector_type(8))) unsigned short u16x8;
typedef __attribute__((ext_vector_type(4))) float f32x4;

__device__ __forceinline__ short f2bf(float x) {
    unsigned u = __float_as_uint(x);
    unsigned r = (u + 0x7fffu + ((u >> 16) & 1u)) >> 16;  // RNE
    return (short)r;
}
__device__ __forceinline__ float bf2f(unsigned short u) {
    return __uint_as_float((unsigned)u << 16);
}

// ---------------- int64-vs-int32 edge_index detection ----------------
__global__ void detect_kernel(const unsigned int* e32, int* flag) {
    __shared__ int nz;
    if (threadIdx.x == 0) nz = 0;
    __syncthreads();
    if (e32[2 * threadIdx.x + 1] != 0) nz = 1;
    __syncthreads();
    if (threadIdx.x == 0) *flag = (nz == 0) ? 1 : 0;
}

__device__ __forceinline__ int load_idx(const void* e, int is64, long long i) {
    if (is64) return (int)((const long long*)e)[i];
    return ((const int*)e)[i];
}

// ================= bucketed CSR build (r0-proven) =================
#define NBLK 256  // blocks for count & scatter (pbh rows)

// ---- B1: per-block LDS bucket histogram -> global pbh[block][512] ----
__global__ __launch_bounds__(256) void bucket_count_kernel(
    const void* edges, const int* flag, int* pbh, int E, int shift) {
    __shared__ int h[512];
    for (int i = threadIdx.x; i < 512; i += 256) h[i] = 0;
    __syncthreads();
    int is64 = *flag;
    int chunk = (E + gridDim.x - 1) / gridDim.x;
    int s0 = blockIdx.x * chunk;
    int s1 = min(E, s0 + chunk);
    for (int e = s0 + (int)threadIdx.x; e < s1; e += 256) {
        int d = load_idx(edges, is64, (long long)E + e);
        atomicAdd(&h[d >> shift], 1);
    }
    __syncthreads();
    for (int i = threadIdx.x; i < 512; i += 256) pbh[blockIdx.x * 512 + i] = h[i];
}

// ---- B2a: per-bucket column scan ----
__global__ __launch_bounds__(256) void colscan_kernel(int* pbh, int* btot) {
    int b = blockIdx.x;  // bucket
    int k = threadIdx.x; // count-block
    __shared__ int sA[256], sB[256];
    int v = pbh[k * 512 + b];
    sA[k] = v;
    __syncthreads();
    int* src = sA;
    int* dst = sB;
    for (int d = 1; d < 256; d <<= 1) {
        dst[k] = src[k] + (k >= d ? src[k - d] : 0);
        __syncthreads();
        int* t = src; src = dst; dst = t;
    }
    pbh[k * 512 + b] = src[k] - v;  // exclusive prefix within column
    if (k == 255) btot[b] = src[255];
}

// ---- B2b: single-block scan of 512 bucket totals -> bbase ----
__global__ __launch_bounds__(512) void basescan_kernel(const int* btot, int* bbase, int E) {
    __shared__ int sA[512], sB[512];
    int b = threadIdx.x;
    int v = btot[b];
    sA[b] = v;
    __syncthreads();
    int* src = sA;
    int* dst = sB;
    for (int d = 1; d < 512; d <<= 1) {
        dst[b] = src[b] + (b >= d ? src[b - d] : 0);
        __syncthreads();
        int* t = src; src = dst; dst = t;
    }
    bbase[b] = src[b] - v;
    if (b == 0) bbase[512] = E;
}

// ---- B3: scatter, single edge pass, LDS cursors = pbh prefix + bbase ----
__global__ __launch_bounds__(256) void bucket_scatter_kernel(
    const void* edges, const int* flag, const int* pbh, const int* bbase,
    unsigned* staging, int E, int shift) {
    __shared__ int cur[512];
    for (int i = threadIdx.x; i < 512; i += 256)
        cur[i] = pbh[blockIdx.x * 512 + i] + bbase[i];
    __syncthreads();
    int is64 = *flag;
    int chunk = (E + gridDim.x - 1) / gridDim.x;
    int s0 = blockIdx.x * chunk;
    int s1 = min(E, s0 + chunk);
    unsigned mask = (unsigned)((1 << shift) - 1);
    for (int e = s0 + (int)threadIdx.x; e < s1; e += 256) {
        int s = load_idx(edges, is64, e);
        int d = load_idx(edges, is64, (long long)E + e);
        int b = d >> shift;
        int pos = atomicAdd(&cur[b], 1);  // LDS atomic
        staging[pos] = ((unsigned)s << shift) | ((unsigned)d & mask);
    }
}

// ---- B4: one block per bucket: LDS counting sort by local dst ----
__global__ __launch_bounds__(256) void bucket_fill_kernel(
    const unsigned* __restrict__ staging, const int* __restrict__ bbase,
    int* __restrict__ offs, float* __restrict__ dinv, int* __restrict__ srcs,
    int shift, int n, int E) {
    int b = blockIdx.x;
    int bstart = bbase[b], bend = bbase[b + 1];
    int bsz = 1 << shift;
    unsigned mask = (unsigned)(bsz - 1);
    int v0 = b << shift;
    int nloc = min(bsz, n - v0);

    __shared__ int cnt[512], cur[512], sA[512], sB[512];
    for (int i = threadIdx.x; i < bsz; i += 256) cnt[i] = 0;
    __syncthreads();
    for (int idx = bstart + (int)threadIdx.x; idx < bend; idx += 256)
        atomicAdd(&cnt[staging[idx] & mask], 1);
    __syncthreads();
    for (int i = threadIdx.x; i < bsz; i += 256) sA[i] = cnt[i];
    __syncthreads();
    int* src = sA;
    int* dst = sB;
    for (int d = 1; d < bsz; d <<= 1) {
        for (int i = threadIdx.x; i < bsz; i += 256)
            dst[i] = src[i] + (i >= d ? src[i - d] : 0);
        __syncthreads();
        int* t = src; src = dst; dst = t;
    }
    for (int i = threadIdx.x; i < bsz; i += 256) {
        int excl = src[i] - cnt[i];
        cur[i] = excl;
        if (i < nloc) {
            offs[v0 + i] = bstart + excl;
            dinv[v0 + i] = rsqrtf((float)(cnt[i] + 1));
        }
    }
    if (b == 0 && threadIdx.x == 0) offs[n] = E;
    __syncthreads();
    for (int idx = bstart + (int)threadIdx.x; idx < bend; idx += 256) {
        unsigned u = staging[idx];
        int ld = (int)(u & mask);
        int pos = atomicAdd(&cur[ld], 1);
        srcs[bstart + pos] = (int)(u >> shift);
    }
}

// ---------------- fused (BN+ReLU) -> [n,64]@[64,64] MFMA matmul ----------------
// BN stats arrive as 16 slabs of 128 floats (sum|sumsq); each block reduces
// them into LDS once (8 KB L2-broadcast) -- replaces the redstats kernel.
__global__ __launch_bounds__(256) void mm_bn_kernel(
    const float* __restrict__ Xf, const unsigned short* __restrict__ Xb, int x_is_bf16,
    const float* __restrict__ W,
    const float* __restrict__ slabs, const float* __restrict__ gamma,
    const float* __restrict__ beta, int use_bn, float inv_n,
    const float* __restrict__ dinv,
    unsigned short* __restrict__ Y, int n) {
    int lane = threadIdx.x & 63;
    int m = lane & 15;
    int quad = lane >> 4;

    __shared__ float cn[128];
    if (use_bn) {
        if (threadIdx.x < 128) {
            float s = 0.f;
#pragma unroll
            for (int k = 0; k < 16; k++) s += slabs[k * 128 + (int)threadIdx.x];
            cn[threadIdx.x] = s;
        }
        __syncthreads();
    }

    float sc[16], sh[16];
#pragma unroll
    for (int s = 0; s < 2; s++) {
#pragma unroll
        for (int j = 0; j < 8; j++) {
            float scale = 1.f, shift = 0.f;
            if (use_bn) {
                int f = s * 32 + quad * 8 + j;
                float mean = cn[f] * inv_n;
                float var = cn[64 + f] * inv_n - mean * mean;
                float rs = rsqrtf(var + 1e-5f);
                scale = rs * gamma[f];
                shift = beta[f] - mean * scale;
            }
            sc[s * 8 + j] = scale;
            sh[s * 8 + j] = shift;
        }
    }

    bf16x8 bfrag[4][2];
#pragma unroll
    for (int nt = 0; nt < 4; nt++) {
#pragma unroll
        for (int s = 0; s < 2; s++) {
#pragma unroll
            for (int j = 0; j < 8; j++) {
                int k = s * 32 + quad * 8 + j;
                bfrag[nt][s][j] = f2bf(W[k * 64 + nt * 16 + m]);
            }
        }
    }

    int wave = blockIdx.x * 4 + (threadIdx.x >> 6);
    int nwaves = gridDim.x * 4;
    int ntiles = (n + 15) >> 4;
    const f32x4 zero = {0.f, 0.f, 0.f, 0.f};

    for (int t = wave; t < ntiles; t += nwaves) {
        int r = t * 16 + m;
        if (r >= n) r = n - 1;  // redundant load; stores are guarded
        float av[16];
        if (x_is_bf16) {
            const unsigned short* xr = Xb + (long long)r * 64;
            u16x8 u0 = *(const u16x8*)(xr + quad * 8);
            u16x8 u1 = *(const u16x8*)(xr + 32 + quad * 8);
#pragma unroll
            for (int j = 0; j < 8; j++) {
                av[j] = bf2f(u0[j]);
                av[8 + j] = bf2f(u1[j]);
            }
        } else {
            const float* xr = Xf + (long long)r * 64;
            f32x4 a0 = *(const f32x4*)(xr + quad * 8);
            f32x4 a1 = *(const f32x4*)(xr + quad * 8 + 4);
            f32x4 a2 = *(const f32x4*)(xr + 32 + quad * 8);
            f32x4 a3 = *(const f32x4*)(xr + 32 + quad * 8 + 4);
#pragma unroll
            for (int j = 0; j < 4; j++) {
                av[j] = a0[j];
                av[4 + j] = a1[j];
                av[8 + j] = a2[j];
                av[12 + j] = a3[j];
            }
        }
        bf16x8 A0, A1;
#pragma unroll
        for (int j = 0; j < 8; j++) {
            float v0 = av[j] * sc[j] + sh[j];
            float v1 = av[8 + j] * sc[8 + j] + sh[8 + j];
            if (use_bn) {
                v0 = fmaxf(v0, 0.f);
                v1 = fmaxf(v1, 0.f);
            }
            A0[j] = f2bf(v0);
            A1[j] = f2bf(v1);
        }

        f32x4 acc[4];
#pragma unroll
        for (int nt = 0; nt < 4; nt++) {
            acc[nt] = __builtin_amdgcn_mfma_f32_16x16x32_bf16(A0, bfrag[nt][0], zero, 0, 0, 0);
            acc[nt] = __builtin_amdgcn_mfma_f32_16x16x32_bf16(A1, bfrag[nt][1], acc[nt], 0, 0, 0);
        }

        int row0 = t * 16 + quad * 4;
        float dv[4];
#pragma unroll
        for (int i = 0; i < 4; i++) {
            int rr = row0 + i;
            dv[i] = (rr < n) ? dinv[rr] : 0.f;
        }
#pragma unroll
        for (int nt = 0; nt < 4; nt++) {
#pragma unroll
            for (int i = 0; i < 4; i++) {
                int rr = row0 + i;
                if (rr < n)
                    Y[(long long)rr * 64 + nt * 16 + m] = (unsigned short)f2bf(acc[nt][i] * dv[i]);
            }
        }
    }
}

// ---------------- aggregation: r0 geometry, 16-deep single-volley batches ----
// One wave per dst node, lane = feature. Per batch: one contiguous scalar
// index load (srcs[j..j+15], over-read safe via +16 pad), dead slots select
// (scalar) to the zero row at table row n -> 16 unconditional gathers issued
// back-to-back, one waitcnt, pure add tree. 2x the in-flight lines of r0's
// 8+8 split with zero extra VALU.
__global__ __launch_bounds__(256) void agg_kernel(const unsigned short* __restrict__ T,
                                                  const int* __restrict__ offs,
                                                  const int* __restrict__ srcs,
                                                  const float* __restrict__ dinv,
                                                  const float* __restrict__ bias,
                                                  unsigned short* __restrict__ out16,
                                                  float* __restrict__ out32, int out_bf16,
                                                  float* __restrict__ slabs, int do_stats,
                                                  int n) {
    int v = blockIdx.x * 4 + (threadIdx.x >> 6);
    int lane = threadIdx.x & 63;
    int valid = v < n;
    int vc = valid ? v : n - 1;
    float val;
    {
        float acc = bf2f(T[((unsigned)vc << 6) + lane]);  // self-loop (pre-scaled)
        int j0 = __builtin_amdgcn_readfirstlane(offs[vc]);
        int j1 = __builtin_amdgcn_readfirstlane(offs[vc + 1]);
        for (int j = j0; j < j1; j += 16) {
            int sidx[16];
#pragma unroll
            for (int u = 0; u < 16; u++) {
                int jj = j + u;
                int s = srcs[jj];            // contiguous scalar load (padded)
                sidx[u] = (jj < j1) ? s : n; // scalar select: dead -> zero row
            }
            float t[16];
#pragma unroll
            for (int u = 0; u < 16; u++)
                t[u] = bf2f(T[((unsigned)sidx[u] << 6) + lane]);
            float p0 = (t[0] + t[1]) + (t[2] + t[3]);
            float p1 = (t[4] + t[5]) + (t[6] + t[7]);
            float p2 = (t[8] + t[9]) + (t[10] + t[11]);
            float p3 = (t[12] + t[13]) + (t[14] + t[15]);
            acc += (p0 + p1) + (p2 + p3);
        }
        val = dinv[vc] * acc + bias[lane];
        if (valid) {
            if (out_bf16)
                out16[((unsigned)v << 6) + lane] = (unsigned short)f2bf(val);
            else
                out32[((unsigned)v << 6) + lane] = val;
        }
    }
    if (do_stats) {
        __shared__ float ls[256], lq[256];
        float x = valid ? val : 0.f;
        ls[threadIdx.x] = x;
        lq[threadIdx.x] = x * x;
        __syncthreads();
        int tid = threadIdx.x;
        if (tid < 128) {
            int f = tid & 63;
            const float* a = (tid < 64) ? ls : lq;
            float r = a[f] + a[64 + f] + a[128 + f] + a[192 + f];
            // slab row layout: [sum(64) | sumsq(64)]; tid encodes both halves
            atomicAdd(&slabs[((unsigned)(blockIdx.x & 15)) * 128 + tid], r);
        }
    }
}

// ---------------- host ----------------
extern "C" void kernel_launch(void* const* d_in, const int* in_sizes, int n_in,
                              void* d_out, int out_size, void* d_ws, size_t ws_size,
                              hipStream_t stream) {
    const float* x = (const float*)d_in[0];
    const void* edges = d_in[1];
    const float* W1 = (const float*)d_in[3];
    const float* b1 = (const float*)d_in[4];
    const float* gamma1 = (const float*)d_in[5];
    const float* beta1 = (const float*)d_in[6];
    const float* W2 = (const float*)d_in[7];
    const float* b2 = (const float*)d_in[8];
    const float* gamma2 = (const float*)d_in[9];
    const float* beta2 = (const float*)d_in[10];
    const float* W3 = (const float*)d_in[11];
    const float* b3 = (const float*)d_in[12];

    const int N = in_sizes[0] / D;
    const int E = in_sizes[1] / 2;
    const float inv_n = 1.f / (float)N;

    int shift = 8;
    while ((((long long)N - 1) >> shift) + 1 > 512) shift++;
    const int nbuk = (int)(((long long)N - 1) >> shift) + 1;

    char* ws = (char*)d_ws;
    size_t off = 0;
    auto alloc = [&](size_t bytes) -> void* {
        void* p = ws + off;
        off = (off + bytes + 255) & ~(size_t)255;
        return p;
    };
    float*    dinv    = (float*)   alloc((size_t)N * 4);
    int*      offs    = (int*)     alloc((size_t)(N + 1) * 4);
    int*      srcs    = (int*)     alloc(((size_t)E + 16) * 4);  // +16 over-read pad
    unsigned* staging = (unsigned*)alloc((size_t)E * 4);
    int*      pbh     = (int*)     alloc((size_t)NBLK * 512 * 4);
    int*      btot    = (int*)     alloc(512 * 4);
    int*      bbase   = (int*)     alloc(513 * 4);
    int*      flag    = (int*)     alloc(4);
    float*    slabs   = (float*)   alloc((size_t)2 * 16 * 128 * 4);  // L1 | L2 slab regions
    unsigned short* bufA = (unsigned short*)alloc((size_t)(N + 1) * D * 2);  // + zero row
    unsigned short* hbuf = (unsigned short*)alloc((size_t)N * D * 2);  // bf16 node feats
    float*    outf    = (float*)d_out;  // final fp32 output

    const int AGGB = (N + 3) / 4;  // one wave per node (r0-proven residency)
    const int MMB  = 782;          // 6250 tiles / (782*4 waves) = 2 tiles/wave

    // ---- bucketed CSR build (once, reused 3x; zero global atomics) ----
    detect_kernel<<<1, 256, 0, stream>>>((const unsigned int*)edges, flag);
    bucket_count_kernel<<<NBLK, 256, 0, stream>>>(edges, flag, pbh, E, shift);
    colscan_kernel<<<512, 256, 0, stream>>>(pbh, btot);
    basescan_kernel<<<1, 512, 0, stream>>>(btot, bbase, E);
    bucket_scatter_kernel<<<NBLK, 256, 0, stream>>>(edges, flag, pbh, bbase, staging, E, shift);
    bucket_fill_kernel<<<nbuk, 256, 0, stream>>>(staging, bbase, offs, dinv, srcs, shift, N, E);
    hipMemsetAsync(slabs, 0, (size_t)2 * 16 * 128 * 4, stream);
    hipMemsetAsync(bufA + (size_t)N * D, 0, D * 2, stream);  // zero row (gather sink)

    // ---- layer 1 (x fp32 in; agg fuses BN1 stats) ----
    mm_bn_kernel<<<MMB, 256, 0, stream>>>(x, nullptr, 0, W1, nullptr, nullptr, nullptr, 0,
                                          inv_n, dinv, bufA, N);
    agg_kernel<<<AGGB, 256, 0, stream>>>(bufA, offs, srcs, dinv, b1, hbuf, nullptr, 1,
                                         slabs, 1, N);

    // ---- layer 2 (hbuf bf16 in; BN1 via slab-reduce in mm; agg fuses BN2 stats) ----
    mm_bn_kernel<<<MMB, 256, 0, stream>>>(nullptr, hbuf, 1, W2, slabs, gamma1, beta1, 1,
                                          inv_n, dinv, bufA, N);
    agg_kernel<<<AGGB, 256, 0, stream>>>(bufA, offs, srcs, dinv, b2, hbuf, nullptr, 1,
                                         slabs + 16 * 128, 1, N);

    // ---- layer 3 (hbuf bf16 in; BN2 via slab-reduce; fp32 out to d_out) ----
    mm_bn_kernel<<<MMB, 256, 0, stream>>>(nullptr, hbuf, 1, W3, slabs + 16 * 128, gamma2, beta2, 1,
                                          inv_n, dinv, bufA, N);
    agg_kernel<<<AGGB, 256, 0, stream>>>(bufA, offs, srcs, dinv, b3, nullptr, outf, 0,
                                         nullptr, 0, N);
}

// Round 6
// 299.805 us; speedup vs baseline: 1.4906x; 1.0226x over previous
//
#include <hip/hip_runtime.h>
#include <hip/hip_bf16.h>

#define D 64

typedef __attribute__((ext_vector_type(8))) short bf16x8;
typedef __attribute__((ext_vector_type(8))) unsigned short u16x8;
typedef __attribute__((ext_vector_type(4))) float f32x4;

__device__ __forceinline__ short f2bf(float x) {
    unsigned u = __float_as_uint(x);
    unsigned r = (u + 0x7fffu + ((u >> 16) & 1u)) >> 16;  // RNE
    return (short)r;
}
__device__ __forceinline__ float bf2f(unsigned short u) {
    return __uint_as_float((unsigned)u << 16);
}

// ---------------- int64-vs-int32 edge_index detection (inlined) --------------
// Same rule as the old detect_kernel: high words of the first 256 int64 slots
// all zero -> int64 data. Each block re-derives it from the L2-hot first 2KB.
__device__ __forceinline__ int block_detect_is64(const unsigned* e32) {
    __shared__ int nz;
    if (threadIdx.x == 0) nz = 0;
    __syncthreads();
    if (threadIdx.x < 256 && e32[2 * threadIdx.x + 1] != 0) nz = 1;
    __syncthreads();
    return nz == 0;
}

__device__ __forceinline__ int load_idx(const void* e, int is64, long long i) {
    if (is64) return (int)((const long long*)e)[i];
    return ((const int*)e)[i];
}

// ================= bucketed CSR build (r0-proven) =================
#define NBLK 256  // blocks for count & scatter (pbh rows)

// ---- B1: per-block LDS bucket histogram -> global pbh[block][512] ----
// Block 0 also zeroes the BN stat slabs (needed much later by agg).
__global__ __launch_bounds__(256) void bucket_count_kernel(
    const void* edges, int* pbh, float* slabs, int E, int shift) {
    int is64 = block_detect_is64((const unsigned*)edges);
    if (blockIdx.x == 0)
        for (int i = threadIdx.x; i < 2 * 16 * 128; i += 256) slabs[i] = 0.f;
    __shared__ int h[512];
    for (int i = threadIdx.x; i < 512; i += 256) h[i] = 0;
    __syncthreads();
    int chunk = (E + gridDim.x - 1) / gridDim.x;
    int s0 = blockIdx.x * chunk;
    int s1 = min(E, s0 + chunk);
    for (int e = s0 + (int)threadIdx.x; e < s1; e += 256) {
        int d = load_idx(edges, is64, (long long)E + e);
        atomicAdd(&h[d >> shift], 1);
    }
    __syncthreads();
    for (int i = threadIdx.x; i < 512; i += 256) pbh[blockIdx.x * 512 + i] = h[i];
}

// ---- B2a: per-bucket column scan ----
__global__ __launch_bounds__(256) void colscan_kernel(int* pbh, int* btot) {
    int b = blockIdx.x;  // bucket
    int k = threadIdx.x; // count-block
    __shared__ int sA[256], sB[256];
    int v = pbh[k * 512 + b];
    sA[k] = v;
    __syncthreads();
    int* src = sA;
    int* dst = sB;
    for (int d = 1; d < 256; d <<= 1) {
        dst[k] = src[k] + (k >= d ? src[k - d] : 0);
        __syncthreads();
        int* t = src; src = dst; dst = t;
    }
    pbh[k * 512 + b] = src[k] - v;  // exclusive prefix within column
    if (k == 255) btot[b] = src[255];
}

// ---- B2b: single-block scan of 512 bucket totals -> bbase ----
__global__ __launch_bounds__(512) void basescan_kernel(const int* btot, int* bbase, int E) {
    __shared__ int sA[512], sB[512];
    int b = threadIdx.x;
    int v = btot[b];
    sA[b] = v;
    __syncthreads();
    int* src = sA;
    int* dst = sB;
    for (int d = 1; d < 512; d <<= 1) {
        dst[b] = src[b] + (b >= d ? src[b - d] : 0);
        __syncthreads();
        int* t = src; src = dst; dst = t;
    }
    bbase[b] = src[b] - v;
    if (b == 0) bbase[512] = E;
}

// ---- B3: scatter, single edge pass, LDS cursors = pbh prefix + bbase ----
__global__ __launch_bounds__(256) void bucket_scatter_kernel(
    const void* edges, const int* pbh, const int* bbase,
    unsigned* staging, int E, int shift) {
    int is64 = block_detect_is64((const unsigned*)edges);
    __shared__ int cur[512];
    for (int i = threadIdx.x; i < 512; i += 256)
        cur[i] = pbh[blockIdx.x * 512 + i] + bbase[i];
    __syncthreads();
    int chunk = (E + gridDim.x - 1) / gridDim.x;
    int s0 = blockIdx.x * chunk;
    int s1 = min(E, s0 + chunk);
    unsigned mask = (unsigned)((1 << shift) - 1);
    for (int e = s0 + (int)threadIdx.x; e < s1; e += 256) {
        int s = load_idx(edges, is64, e);
        int d = load_idx(edges, is64, (long long)E + e);
        int b = d >> shift;
        int pos = atomicAdd(&cur[b], 1);  // LDS atomic
        staging[pos] = ((unsigned)s << shift) | ((unsigned)d & mask);
    }
}

// ---- B4: one block per bucket: LDS counting sort by local dst ----
// Block 0 also zeroes the gather-sink row (row n of the message table).
__global__ __launch_bounds__(256) void bucket_fill_kernel(
    const unsigned* __restrict__ staging, const int* __restrict__ bbase,
    int* __restrict__ offs, float* __restrict__ dinv, int* __restrict__ srcs,
    unsigned short* __restrict__ zrow, int shift, int n, int E) {
    int b = blockIdx.x;
    if (b == 0 && threadIdx.x < 64) zrow[threadIdx.x] = 0;
    int bstart = bbase[b], bend = bbase[b + 1];
    int bsz = 1 << shift;
    unsigned mask = (unsigned)(bsz - 1);
    int v0 = b << shift;
    int nloc = min(bsz, n - v0);

    __shared__ int cnt[512], cur[512], sA[512], sB[512];
    for (int i = threadIdx.x; i < bsz; i += 256) cnt[i] = 0;
    __syncthreads();
    for (int idx = bstart + (int)threadIdx.x; idx < bend; idx += 256)
        atomicAdd(&cnt[staging[idx] & mask], 1);
    __syncthreads();
    for (int i = threadIdx.x; i < bsz; i += 256) sA[i] = cnt[i];
    __syncthreads();
    int* src = sA;
    int* dst = sB;
    for (int d = 1; d < bsz; d <<= 1) {
        for (int i = threadIdx.x; i < bsz; i += 256)
            dst[i] = src[i] + (i >= d ? src[i - d] : 0);
        __syncthreads();
        int* t = src; src = dst; dst = t;
    }
    for (int i = threadIdx.x; i < bsz; i += 256) {
        int excl = src[i] - cnt[i];
        cur[i] = excl;
        if (i < nloc) {
            offs[v0 + i] = bstart + excl;
            dinv[v0 + i] = rsqrtf((float)(cnt[i] + 1));
        }
    }
    if (b == 0 && threadIdx.x == 0) offs[n] = E;
    __syncthreads();
    for (int idx = bstart + (int)threadIdx.x; idx < bend; idx += 256) {
        unsigned u = staging[idx];
        int ld = (int)(u & mask);
        int pos = atomicAdd(&cur[ld], 1);
        srcs[bstart + pos] = (int)(u >> shift);
    }
}

// ---------------- fused (BN+ReLU) -> [n,64]@[64,64] MFMA matmul ----------------
// BN stats arrive as 16 slabs of 128 floats (sum|sumsq); each block reduces
// them into LDS once. Epilogue: per-wave LDS transpose tile (72-ushort padded
// rows, same-wave ds_write->ds_read, no barrier) -> two coalesced u16x8
// stores/lane (full 128B rows) instead of 16 guarded 2B scattered stores.
__global__ __launch_bounds__(256) void mm_bn_kernel(
    const float* __restrict__ Xf, const unsigned short* __restrict__ Xb, int x_is_bf16,
    const float* __restrict__ W,
    const float* __restrict__ slabs, const float* __restrict__ gamma,
    const float* __restrict__ beta, int use_bn, float inv_n,
    const float* __restrict__ dinv,
    unsigned short* __restrict__ Y, int n) {
    int lane = threadIdx.x & 63;
    int m = lane & 15;
    int quad = lane >> 4;
    int w = threadIdx.x >> 6;

    __shared__ float cn[128];
    __shared__ __align__(16) unsigned short ty[4][16][72];

    if (use_bn) {
        if (threadIdx.x < 128) {
            float s = 0.f;
#pragma unroll
            for (int k = 0; k < 16; k++) s += slabs[k * 128 + (int)threadIdx.x];
            cn[threadIdx.x] = s;
        }
        __syncthreads();
    }

    float sc[16], sh[16];
#pragma unroll
    for (int s = 0; s < 2; s++) {
#pragma unroll
        for (int j = 0; j < 8; j++) {
            float scale = 1.f, shift = 0.f;
            if (use_bn) {
                int f = s * 32 + quad * 8 + j;
                float mean = cn[f] * inv_n;
                float var = cn[64 + f] * inv_n - mean * mean;
                float rs = rsqrtf(var + 1e-5f);
                scale = rs * gamma[f];
                shift = beta[f] - mean * scale;
            }
            sc[s * 8 + j] = scale;
            sh[s * 8 + j] = shift;
        }
    }

    bf16x8 bfrag[4][2];
#pragma unroll
    for (int nt = 0; nt < 4; nt++) {
#pragma unroll
        for (int s = 0; s < 2; s++) {
#pragma unroll
            for (int j = 0; j < 8; j++) {
                int k = s * 32 + quad * 8 + j;
                bfrag[nt][s][j] = f2bf(W[k * 64 + nt * 16 + m]);
            }
        }
    }

    int wave = blockIdx.x * 4 + w;
    int nwaves = gridDim.x * 4;
    int ntiles = (n + 15) >> 4;
    const f32x4 zero = {0.f, 0.f, 0.f, 0.f};

    for (int t = wave; t < ntiles; t += nwaves) {
        int r = t * 16 + m;
        if (r >= n) r = n - 1;  // redundant load; stores are guarded
        float av[16];
        if (x_is_bf16) {
            const unsigned short* xr = Xb + (long long)r * 64;
            u16x8 u0 = *(const u16x8*)(xr + quad * 8);
            u16x8 u1 = *(const u16x8*)(xr + 32 + quad * 8);
#pragma unroll
            for (int j = 0; j < 8; j++) {
                av[j] = bf2f(u0[j]);
                av[8 + j] = bf2f(u1[j]);
            }
        } else {
            const float* xr = Xf + (long long)r * 64;
            f32x4 a0 = *(const f32x4*)(xr + quad * 8);
            f32x4 a1 = *(const f32x4*)(xr + quad * 8 + 4);
            f32x4 a2 = *(const f32x4*)(xr + 32 + quad * 8);
            f32x4 a3 = *(const f32x4*)(xr + 32 + quad * 8 + 4);
#pragma unroll
            for (int j = 0; j < 4; j++) {
                av[j] = a0[j];
                av[4 + j] = a1[j];
                av[8 + j] = a2[j];
                av[12 + j] = a3[j];
            }
        }
        bf16x8 A0, A1;
#pragma unroll
        for (int j = 0; j < 8; j++) {
            float v0 = av[j] * sc[j] + sh[j];
            float v1 = av[8 + j] * sc[8 + j] + sh[8 + j];
            if (use_bn) {
                v0 = fmaxf(v0, 0.f);
                v1 = fmaxf(v1, 0.f);
            }
            A0[j] = f2bf(v0);
            A1[j] = f2bf(v1);
        }

        f32x4 acc[4];
#pragma unroll
        for (int nt = 0; nt < 4; nt++) {
            acc[nt] = __builtin_amdgcn_mfma_f32_16x16x32_bf16(A0, bfrag[nt][0], zero, 0, 0, 0);
            acc[nt] = __builtin_amdgcn_mfma_f32_16x16x32_bf16(A1, bfrag[nt][1], acc[nt], 0, 0, 0);
        }

        // epilogue: dinv-scale, bf16-convert, LDS transpose, coalesced store
        int row0 = t * 16 + quad * 4;
        float dvv[4];
#pragma unroll
        for (int i = 0; i < 4; i++) {
            int rr = row0 + i;
            dvv[i] = (rr < n) ? dinv[rr] : 0.f;
        }
#pragma unroll
        for (int nt = 0; nt < 4; nt++) {
#pragma unroll
            for (int i = 0; i < 4; i++)
                ty[w][quad * 4 + i][nt * 16 + m] =
                    (unsigned short)f2bf(acc[nt][i] * dvv[i]);
        }
        // same-wave LDS read-back (compiler orders via lgkmcnt; no barrier:
        // ty[w] is wave-exclusive and trip counts differ across waves)
        int lr = lane >> 2, lc = lane & 3;
        u16x8 o0 = *(const u16x8*)&ty[w][lr][lc * 16];
        u16x8 o1 = *(const u16x8*)&ty[w][lr][lc * 16 + 8];
        int rr = t * 16 + lr;
        if (rr < n) {
            *(u16x8*)(Y + ((unsigned)rr << 6) + lc * 16) = o0;
            *(u16x8*)(Y + ((unsigned)rr << 6) + lc * 16 + 8) = o1;
        }
    }
}

// ---------------- aggregation: r0 geometry, 16-deep single-volley batches ----
// UNCHANGED (control): at the ~2.2 TB/s random-128B-gather ceiling; two
// structurally different versions (r0 8+8, r5 16-volley) both pinned there.
__global__ __launch_bounds__(256) void agg_kernel(const unsigned short* __restrict__ T,
                                                  const int* __restrict__ offs,
                                                  const int* __restrict__ srcs,
                                                  const float* __restrict__ dinv,
                                                  const float* __restrict__ bias,
                                                  unsigned short* __restrict__ out16,
                                                  float* __restrict__ out32, int out_bf16,
                                                  float* __restrict__ slabs, int do_stats,
                                                  int n) {
    int v = blockIdx.x * 4 + (threadIdx.x >> 6);
    int lane = threadIdx.x & 63;
    int valid = v < n;
    int vc = valid ? v : n - 1;
    float val;
    {
        float acc = bf2f(T[((unsigned)vc << 6) + lane]);  // self-loop (pre-scaled)
        int j0 = __builtin_amdgcn_readfirstlane(offs[vc]);
        int j1 = __builtin_amdgcn_readfirstlane(offs[vc + 1]);
        for (int j = j0; j < j1; j += 16) {
            int sidx[16];
#pragma unroll
            for (int u = 0; u < 16; u++) {
                int jj = j + u;
                int s = srcs[jj];            // contiguous scalar load (padded)
                sidx[u] = (jj < j1) ? s : n; // scalar select: dead -> zero row
            }
            float t[16];
#pragma unroll
            for (int u = 0; u < 16; u++)
                t[u] = bf2f(T[((unsigned)sidx[u] << 6) + lane]);
            float p0 = (t[0] + t[1]) + (t[2] + t[3]);
            float p1 = (t[4] + t[5]) + (t[6] + t[7]);
            float p2 = (t[8] + t[9]) + (t[10] + t[11]);
            float p3 = (t[12] + t[13]) + (t[14] + t[15]);
            acc += (p0 + p1) + (p2 + p3);
        }
        val = dinv[vc] * acc + bias[lane];
        if (valid) {
            if (out_bf16)
                out16[((unsigned)v << 6) + lane] = (unsigned short)f2bf(val);
            else
                out32[((unsigned)v << 6) + lane] = val;
        }
    }
    if (do_stats) {
        __shared__ float ls[256], lq[256];
        float x = valid ? val : 0.f;
        ls[threadIdx.x] = x;
        lq[threadIdx.x] = x * x;
        __syncthreads();
        int tid = threadIdx.x;
        if (tid < 128) {
            int f = tid & 63;
            const float* a = (tid < 64) ? ls : lq;
            float r = a[f] + a[64 + f] + a[128 + f] + a[192 + f];
            // slab row layout: [sum(64) | sumsq(64)]; tid encodes both halves
            atomicAdd(&slabs[((unsigned)(blockIdx.x & 15)) * 128 + tid], r);
        }
    }
}

// ---------------- host ----------------
extern "C" void kernel_launch(void* const* d_in, const int* in_sizes, int n_in,
                              void* d_out, int out_size, void* d_ws, size_t ws_size,
                              hipStream_t stream) {
    const float* x = (const float*)d_in[0];
    const void* edges = d_in[1];
    const float* W1 = (const float*)d_in[3];
    const float* b1 = (const float*)d_in[4];
    const float* gamma1 = (const float*)d_in[5];
    const float* beta1 = (const float*)d_in[6];
    const float* W2 = (const float*)d_in[7];
    const float* b2 = (const float*)d_in[8];
    const float* gamma2 = (const float*)d_in[9];
    const float* beta2 = (const float*)d_in[10];
    const float* W3 = (const float*)d_in[11];
    const float* b3 = (const float*)d_in[12];

    const int N = in_sizes[0] / D;
    const int E = in_sizes[1] / 2;
    const float inv_n = 1.f / (float)N;

    int shift = 8;
    while ((((long long)N - 1) >> shift) + 1 > 512) shift++;
    const int nbuk = (int)(((long long)N - 1) >> shift) + 1;

    char* ws = (char*)d_ws;
    size_t off = 0;
    auto alloc = [&](size_t bytes) -> void* {
        void* p = ws + off;
        off = (off + bytes + 255) & ~(size_t)255;
        return p;
    };
    float*    dinv    = (float*)   alloc((size_t)N * 4);
    int*      offs    = (int*)     alloc((size_t)(N + 1) * 4);
    int*      srcs    = (int*)     alloc(((size_t)E + 16) * 4);  // +16 over-read pad
    unsigned* staging = (unsigned*)alloc((size_t)E * 4);
    int*      pbh     = (int*)     alloc((size_t)NBLK * 512 * 4);
    int*      btot    = (int*)     alloc(512 * 4);
    int*      bbase   = (int*)     alloc(513 * 4);
    float*    slabs   = (float*)   alloc((size_t)2 * 16 * 128 * 4);  // L1 | L2 slab regions
    unsigned short* bufA = (unsigned short*)alloc((size_t)(N + 1) * D * 2);  // + zero row
    unsigned short* hbuf = (unsigned short*)alloc((size_t)N * D * 2);  // bf16 node feats
    float*    outf    = (float*)d_out;  // final fp32 output

    const int AGGB = (N + 3) / 4;           // one wave per node (proven residency)
    const int MMB  = (((N + 15) >> 4) + 3) / 4;  // one 16-row tile per wave

    // ---- bucketed CSR build (once, reused 3x; zero global atomics) ----
    // detect folded into count/scatter; slab-zero into count; zero-row into fill
    bucket_count_kernel<<<NBLK, 256, 0, stream>>>(edges, pbh, slabs, E, shift);
    colscan_kernel<<<512, 256, 0, stream>>>(pbh, btot);
    basescan_kernel<<<1, 512, 0, stream>>>(btot, bbase, E);
    bucket_scatter_kernel<<<NBLK, 256, 0, stream>>>(edges, pbh, bbase, staging, E, shift);
    bucket_fill_kernel<<<nbuk, 256, 0, stream>>>(staging, bbase, offs, dinv, srcs,
                                                 bufA + (size_t)N * D, shift, N, E);

    // ---- layer 1 (x fp32 in; agg fuses BN1 stats) ----
    mm_bn_kernel<<<MMB, 256, 0, stream>>>(x, nullptr, 0, W1, nullptr, nullptr, nullptr, 0,
                                          inv_n, dinv, bufA, N);
    agg_kernel<<<AGGB, 256, 0, stream>>>(bufA, offs, srcs, dinv, b1, hbuf, nullptr, 1,
                                         slabs, 1, N);

    // ---- layer 2 (hbuf bf16 in; BN1 via slab-reduce in mm; agg fuses BN2 stats) ----
    mm_bn_kernel<<<MMB, 256, 0, stream>>>(nullptr, hbuf, 1, W2, slabs, gamma1, beta1, 1,
                                          inv_n, dinv, bufA, N);
    agg_kernel<<<AGGB, 256, 0, stream>>>(bufA, offs, srcs, dinv, b2, hbuf, nullptr, 1,
                                         slabs + 16 * 128, 1, N);

    // ---- layer 3 (hbuf bf16 in; BN2 via slab-reduce; fp32 out to d_out) ----
    mm_bn_kernel<<<MMB, 256, 0, stream>>>(nullptr, hbuf, 1, W3, slabs + 16 * 128, gamma2, beta2, 1,
                                          inv_n, dinv, bufA, N);
    agg_kernel<<<AGGB, 256, 0, stream>>>(bufA, offs, srcs, dinv, b3, nullptr, outf, 0,
                                         nullptr, 0, N);
}

// Round 7
// 296.616 us; speedup vs baseline: 1.5067x; 1.0108x over previous
//
#include <hip/hip_runtime.h>
#include <hip/hip_bf16.h>

#define D 64

typedef __attribute__((ext_vector_type(8))) short bf16x8;
typedef __attribute__((ext_vector_type(8))) unsigned short u16x8;
typedef __attribute__((ext_vector_type(4))) float f32x4;

__device__ __forceinline__ short f2bf(float x) {
    unsigned u = __float_as_uint(x);
    unsigned r = (u + 0x7fffu + ((u >> 16) & 1u)) >> 16;  // RNE
    return (short)r;
}
__device__ __forceinline__ float bf2f(unsigned short u) {
    return __uint_as_float((unsigned)u << 16);
}

// ---------------- int64-vs-int32 edge_index detection (inlined) --------------
__device__ __forceinline__ int block_detect_is64(const unsigned* e32) {
    __shared__ int nz;
    if (threadIdx.x == 0) nz = 0;
    __syncthreads();
    if (threadIdx.x < 256 && e32[2 * threadIdx.x + 1] != 0) nz = 1;
    __syncthreads();
    return nz == 0;
}

__device__ __forceinline__ int load_idx(const void* e, int is64, long long i) {
    if (is64) return (int)((const long long*)e)[i];
    return ((const int*)e)[i];
}

// ---- W fragment repack: mirror of mm_bn's bfrag indexing, done ONCE ----
// wf layout: [(nt*2+s)*64 + lane] * 8 + j  (lane-consecutive 16B -> coalesced)
__device__ __forceinline__ void repack_w(const float* __restrict__ W,
                                         unsigned short* __restrict__ wf) {
    for (int idx = threadIdx.x; idx < 512; idx += 256) {
        int lane = idx & 63;
        int nts = idx >> 6;
        int s = nts & 1;
        int nt = nts >> 1;
        int quad = lane >> 4;
        int m = lane & 15;
#pragma unroll
        for (int j = 0; j < 8; j++) {
            int k = s * 32 + quad * 8 + j;
            wf[idx * 8 + j] = (unsigned short)f2bf(W[k * 64 + nt * 16 + m]);
        }
    }
}

// ================= bucketed CSR build (r0-proven) =================
#define NBLK 256  // blocks for count & scatter (pbh rows)

// ---- B1: per-block LDS bucket histogram -> global pbh[block][512] ----
// Side jobs: block 0 zeroes BN stat slabs; blocks 1-3 repack W1/W2/W3.
__global__ __launch_bounds__(256) void bucket_count_kernel(
    const void* edges, int* pbh, float* slabs,
    const float* W1, const float* W2, const float* W3,
    unsigned short* wf1, unsigned short* wf2, unsigned short* wf3,
    int E, int shift) {
    int is64 = block_detect_is64((const unsigned*)edges);
    if (blockIdx.x == 0)
        for (int i = threadIdx.x; i < 2 * 16 * 128; i += 256) slabs[i] = 0.f;
    else if (blockIdx.x == 1) repack_w(W1, wf1);
    else if (blockIdx.x == 2) repack_w(W2, wf2);
    else if (blockIdx.x == 3) repack_w(W3, wf3);
    __shared__ int h[512];
    for (int i = threadIdx.x; i < 512; i += 256) h[i] = 0;
    __syncthreads();
    int chunk = (E + gridDim.x - 1) / gridDim.x;
    int s0 = blockIdx.x * chunk;
    int s1 = min(E, s0 + chunk);
    for (int e = s0 + (int)threadIdx.x; e < s1; e += 256) {
        int d = load_idx(edges, is64, (long long)E + e);
        atomicAdd(&h[d >> shift], 1);
    }
    __syncthreads();
    for (int i = threadIdx.x; i < 512; i += 256) pbh[blockIdx.x * 512 + i] = h[i];
}

// ---- B2: per-bucket column scan ----
__global__ __launch_bounds__(256) void colscan_kernel(int* pbh, int* btot) {
    int b = blockIdx.x;  // bucket
    int k = threadIdx.x; // count-block
    __shared__ int sA[256], sB[256];
    int v = pbh[k * 512 + b];
    sA[k] = v;
    __syncthreads();
    int* src = sA;
    int* dst = sB;
    for (int d = 1; d < 256; d <<= 1) {
        dst[k] = src[k] + (k >= d ? src[k - d] : 0);
        __syncthreads();
        int* t = src; src = dst; dst = t;
    }
    pbh[k * 512 + b] = src[k] - v;  // exclusive prefix within column
    if (k == 255) btot[b] = src[255];
}

// ---- B3: scatter; bucket bases derived in-block from btot (no basescan) ----
__global__ __launch_bounds__(256) void bucket_scatter_kernel(
    const void* edges, const int* pbh, const int* btot,
    unsigned* staging, int E, int shift) {
    int is64 = block_detect_is64((const unsigned*)edges);
    __shared__ int sA[512], sB[512], cur[512];
    for (int i = threadIdx.x; i < 512; i += 256) sA[i] = btot[i];
    __syncthreads();
    int* src = sA;
    int* dst = sB;
    for (int d = 1; d < 512; d <<= 1) {
        for (int i = threadIdx.x; i < 512; i += 256)
            dst[i] = src[i] + (i >= d ? src[i - d] : 0);
        __syncthreads();
        int* t = src; src = dst; dst = t;
    }
    // src = inclusive prefix of btot; exclusive base = src[i-1] (0 at i=0)
    for (int i = threadIdx.x; i < 512; i += 256)
        cur[i] = pbh[blockIdx.x * 512 + i] + (i ? src[i - 1] : 0);
    __syncthreads();
    int chunk = (E + gridDim.x - 1) / gridDim.x;
    int s0 = blockIdx.x * chunk;
    int s1 = min(E, s0 + chunk);
    unsigned mask = (unsigned)((1 << shift) - 1);
    for (int e = s0 + (int)threadIdx.x; e < s1; e += 256) {
        int s = load_idx(edges, is64, e);
        int d = load_idx(edges, is64, (long long)E + e);
        int b = d >> shift;
        int pos = atomicAdd(&cur[b], 1);  // LDS atomic
        staging[pos] = ((unsigned)s << shift) | ((unsigned)d & mask);
    }
}

// ---- B4: one block per bucket: LDS counting sort by local dst ----
// Bucket bases derived in-block from btot; block 0 zeroes gather-sink row.
__global__ __launch_bounds__(256) void bucket_fill_kernel(
    const unsigned* __restrict__ staging, const int* __restrict__ btot,
    int* __restrict__ offs, float* __restrict__ dinv, int* __restrict__ srcs,
    unsigned short* __restrict__ zrow, int shift, int n, int E) {
    int b = blockIdx.x;
    if (b == 0 && threadIdx.x < 64) zrow[threadIdx.x] = 0;
    __shared__ int cnt[512], cur[512], sA[512], sB[512];
    __shared__ int s_bstart, s_bend;
    for (int i = threadIdx.x; i < 512; i += 256) sA[i] = btot[i];
    __syncthreads();
    int* src = sA;
    int* dst = sB;
    for (int d = 1; d < 512; d <<= 1) {
        for (int i = threadIdx.x; i < 512; i += 256)
            dst[i] = src[i] + (i >= d ? src[i - d] : 0);
        __syncthreads();
        int* t = src; src = dst; dst = t;
    }
    if (threadIdx.x == 0) {
        s_bstart = b ? src[b - 1] : 0;
        s_bend = src[b];
    }
    __syncthreads();
    int bstart = s_bstart, bend = s_bend;
    int bsz = 1 << shift;
    unsigned mask = (unsigned)(bsz - 1);
    int v0 = b << shift;
    int nloc = min(bsz, n - v0);

    for (int i = threadIdx.x; i < bsz; i += 256) cnt[i] = 0;
    __syncthreads();
    for (int idx = bstart + (int)threadIdx.x; idx < bend; idx += 256)
        atomicAdd(&cnt[staging[idx] & mask], 1);
    __syncthreads();
    for (int i = threadIdx.x; i < bsz; i += 256) sA[i] = cnt[i];
    __syncthreads();
    src = sA;
    dst = sB;
    for (int d = 1; d < bsz; d <<= 1) {
        for (int i = threadIdx.x; i < bsz; i += 256)
            dst[i] = src[i] + (i >= d ? src[i - d] : 0);
        __syncthreads();
        int* t = src; src = dst; dst = t;
    }
    for (int i = threadIdx.x; i < bsz; i += 256) {
        int excl = src[i] - cnt[i];
        cur[i] = excl;
        if (i < nloc) {
            offs[v0 + i] = bstart + excl;
            dinv[v0 + i] = rsqrtf((float)(cnt[i] + 1));
        }
    }
    if (b == 0 && threadIdx.x == 0) offs[n] = E;
    __syncthreads();
    for (int idx = bstart + (int)threadIdx.x; idx < bend; idx += 256) {
        unsigned u = staging[idx];
        int ld = (int)(u & mask);
        int pos = atomicAdd(&cur[ld], 1);
        srcs[bstart + pos] = (int)(u >> shift);
    }
}

// ---------------- fused (BN+ReLU) -> [n,64]@[64,64] MFMA matmul ----------------
// W arrives pre-packed as bf16 fragments (wf, 8KB): prologue = 8 coalesced
// u16x8 loads/lane instead of 64 scattered dwords + 64 converts. BN stats
// arrive as 16 slabs of 128 floats, reduced into LDS per block. Epilogue:
// per-wave LDS transpose tile -> two coalesced u16x8 stores per lane.
__global__ __launch_bounds__(256) void mm_bn_kernel(
    const float* __restrict__ Xf, const unsigned short* __restrict__ Xb, int x_is_bf16,
    const unsigned short* __restrict__ WF,
    const float* __restrict__ slabs, const float* __restrict__ gamma,
    const float* __restrict__ beta, int use_bn, float inv_n,
    const float* __restrict__ dinv,
    unsigned short* __restrict__ Y, int n) {
    int lane = threadIdx.x & 63;
    int m = lane & 15;
    int quad = lane >> 4;
    int w = threadIdx.x >> 6;

    __shared__ float cn[128];
    __shared__ __align__(16) unsigned short ty[4][16][72];

    if (use_bn) {
        if (threadIdx.x < 128) {
            float s = 0.f;
#pragma unroll
            for (int k = 0; k < 16; k++) s += slabs[k * 128 + (int)threadIdx.x];
            cn[threadIdx.x] = s;
        }
        __syncthreads();
    }

    float sc[16], sh[16];
#pragma unroll
    for (int s = 0; s < 2; s++) {
#pragma unroll
        for (int j = 0; j < 8; j++) {
            float scale = 1.f, shift = 0.f;
            if (use_bn) {
                int f = s * 32 + quad * 8 + j;
                float mean = cn[f] * inv_n;
                float var = cn[64 + f] * inv_n - mean * mean;
                float rs = rsqrtf(var + 1e-5f);
                scale = rs * gamma[f];
                shift = beta[f] - mean * scale;
            }
            sc[s * 8 + j] = scale;
            sh[s * 8 + j] = shift;
        }
    }

    bf16x8 bfrag[4][2];
#pragma unroll
    for (int nt = 0; nt < 4; nt++) {
#pragma unroll
        for (int s = 0; s < 2; s++)
            bfrag[nt][s] = *(const bf16x8*)(WF + ((nt * 2 + s) * 64 + lane) * 8);
    }

    int wave = blockIdx.x * 4 + w;
    int nwaves = gridDim.x * 4;
    int ntiles = (n + 15) >> 4;
    const f32x4 zero = {0.f, 0.f, 0.f, 0.f};

    for (int t = wave; t < ntiles; t += nwaves) {
        int r = t * 16 + m;
        if (r >= n) r = n - 1;  // redundant load; stores are guarded
        float av[16];
        if (x_is_bf16) {
            const unsigned short* xr = Xb + (long long)r * 64;
            u16x8 u0 = *(const u16x8*)(xr + quad * 8);
            u16x8 u1 = *(const u16x8*)(xr + 32 + quad * 8);
#pragma unroll
            for (int j = 0; j < 8; j++) {
                av[j] = bf2f(u0[j]);
                av[8 + j] = bf2f(u1[j]);
            }
        } else {
            const float* xr = Xf + (long long)r * 64;
            f32x4 a0 = *(const f32x4*)(xr + quad * 8);
            f32x4 a1 = *(const f32x4*)(xr + quad * 8 + 4);
            f32x4 a2 = *(const f32x4*)(xr + 32 + quad * 8);
            f32x4 a3 = *(const f32x4*)(xr + 32 + quad * 8 + 4);
#pragma unroll
            for (int j = 0; j < 4; j++) {
                av[j] = a0[j];
                av[4 + j] = a1[j];
                av[8 + j] = a2[j];
                av[12 + j] = a3[j];
            }
        }
        bf16x8 A0, A1;
#pragma unroll
        for (int j = 0; j < 8; j++) {
            float v0 = av[j] * sc[j] + sh[j];
            float v1 = av[8 + j] * sc[8 + j] + sh[8 + j];
            if (use_bn) {
                v0 = fmaxf(v0, 0.f);
                v1 = fmaxf(v1, 0.f);
            }
            A0[j] = f2bf(v0);
            A1[j] = f2bf(v1);
        }

        f32x4 acc[4];
#pragma unroll
        for (int nt = 0; nt < 4; nt++) {
            acc[nt] = __builtin_amdgcn_mfma_f32_16x16x32_bf16(A0, bfrag[nt][0], zero, 0, 0, 0);
            acc[nt] = __builtin_amdgcn_mfma_f32_16x16x32_bf16(A1, bfrag[nt][1], acc[nt], 0, 0, 0);
        }

        // epilogue: dinv-scale, bf16-convert, LDS transpose, coalesced store
        int row0 = t * 16 + quad * 4;
        float dvv[4];
#pragma unroll
        for (int i = 0; i < 4; i++) {
            int rr = row0 + i;
            dvv[i] = (rr < n) ? dinv[rr] : 0.f;
        }
#pragma unroll
        for (int nt = 0; nt < 4; nt++) {
#pragma unroll
            for (int i = 0; i < 4; i++)
                ty[w][quad * 4 + i][nt * 16 + m] =
                    (unsigned short)f2bf(acc[nt][i] * dvv[i]);
        }
        // same-wave LDS read-back (compiler orders via lgkmcnt; no barrier:
        // ty[w] is wave-exclusive and trip counts differ across waves)
        int lr = lane >> 2, lc = lane & 3;
        u16x8 o0 = *(const u16x8*)&ty[w][lr][lc * 16];
        u16x8 o1 = *(const u16x8*)&ty[w][lr][lc * 16 + 8];
        int rr = t * 16 + lr;
        if (rr < n) {
            *(u16x8*)(Y + ((unsigned)rr << 6) + lc * 16) = o0;
            *(u16x8*)(Y + ((unsigned)rr << 6) + lc * 16 + 8) = o1;
        }
    }
}

// ---------------- aggregation: r0 geometry, 16-deep single-volley batches ----
// UNCHANGED (control): at the ~2.2 TB/s random-128B-gather ceiling; two
// structurally different versions (r0 8+8, r5 16-volley) both pinned there.
__global__ __launch_bounds__(256) void agg_kernel(const unsigned short* __restrict__ T,
                                                  const int* __restrict__ offs,
                                                  const int* __restrict__ srcs,
                                                  const float* __restrict__ dinv,
                                                  const float* __restrict__ bias,
                                                  unsigned short* __restrict__ out16,
                                                  float* __restrict__ out32, int out_bf16,
                                                  float* __restrict__ slabs, int do_stats,
                                                  int n) {
    int v = blockIdx.x * 4 + (threadIdx.x >> 6);
    int lane = threadIdx.x & 63;
    int valid = v < n;
    int vc = valid ? v : n - 1;
    float val;
    {
        float acc = bf2f(T[((unsigned)vc << 6) + lane]);  // self-loop (pre-scaled)
        int j0 = __builtin_amdgcn_readfirstlane(offs[vc]);
        int j1 = __builtin_amdgcn_readfirstlane(offs[vc + 1]);
        for (int j = j0; j < j1; j += 16) {
            int sidx[16];
#pragma unroll
            for (int u = 0; u < 16; u++) {
                int jj = j + u;
                int s = srcs[jj];            // contiguous scalar load (padded)
                sidx[u] = (jj < j1) ? s : n; // scalar select: dead -> zero row
            }
            float t[16];
#pragma unroll
            for (int u = 0; u < 16; u++)
                t[u] = bf2f(T[((unsigned)sidx[u] << 6) + lane]);
            float p0 = (t[0] + t[1]) + (t[2] + t[3]);
            float p1 = (t[4] + t[5]) + (t[6] + t[7]);
            float p2 = (t[8] + t[9]) + (t[10] + t[11]);
            float p3 = (t[12] + t[13]) + (t[14] + t[15]);
            acc += (p0 + p1) + (p2 + p3);
        }
        val = dinv[vc] * acc + bias[lane];
        if (valid) {
            if (out_bf16)
                out16[((unsigned)v << 6) + lane] = (unsigned short)f2bf(val);
            else
                out32[((unsigned)v << 6) + lane] = val;
        }
    }
    if (do_stats) {
        __shared__ float ls[256], lq[256];
        float x = valid ? val : 0.f;
        ls[threadIdx.x] = x;
        lq[threadIdx.x] = x * x;
        __syncthreads();
        int tid = threadIdx.x;
        if (tid < 128) {
            int f = tid & 63;
            const float* a = (tid < 64) ? ls : lq;
            float r = a[f] + a[64 + f] + a[128 + f] + a[192 + f];
            // slab row layout: [sum(64) | sumsq(64)]; tid encodes both halves
            atomicAdd(&slabs[((unsigned)(blockIdx.x & 15)) * 128 + tid], r);
        }
    }
}

// ---------------- host ----------------
extern "C" void kernel_launch(void* const* d_in, const int* in_sizes, int n_in,
                              void* d_out, int out_size, void* d_ws, size_t ws_size,
                              hipStream_t stream) {
    const float* x = (const float*)d_in[0];
    const void* edges = d_in[1];
    const float* W1 = (const float*)d_in[3];
    const float* b1 = (const float*)d_in[4];
    const float* gamma1 = (const float*)d_in[5];
    const float* beta1 = (const float*)d_in[6];
    const float* W2 = (const float*)d_in[7];
    const float* b2 = (const float*)d_in[8];
    const float* gamma2 = (const float*)d_in[9];
    const float* beta2 = (const float*)d_in[10];
    const float* W3 = (const float*)d_in[11];
    const float* b3 = (const float*)d_in[12];

    const int N = in_sizes[0] / D;
    const int E = in_sizes[1] / 2;
    const float inv_n = 1.f / (float)N;

    int shift = 8;
    while ((((long long)N - 1) >> shift) + 1 > 512) shift++;
    const int nbuk = (int)(((long long)N - 1) >> shift) + 1;

    char* ws = (char*)d_ws;
    size_t off = 0;
    auto alloc = [&](size_t bytes) -> void* {
        void* p = ws + off;
        off = (off + bytes + 255) & ~(size_t)255;
        return p;
    };
    float*    dinv    = (float*)   alloc((size_t)N * 4);
    int*      offs    = (int*)     alloc((size_t)(N + 1) * 4);
    int*      srcs    = (int*)     alloc(((size_t)E + 16) * 4);  // +16 over-read pad
    unsigned* staging = (unsigned*)alloc((size_t)E * 4);
    int*      pbh     = (int*)     alloc((size_t)NBLK * 512 * 4);
    int*      btot    = (int*)     alloc(512 * 4);
    float*    slabs   = (float*)   alloc((size_t)2 * 16 * 128 * 4);  // L1 | L2 slab regions
    unsigned short* wf1 = (unsigned short*)alloc(4096 * 2);  // packed W fragments
    unsigned short* wf2 = (unsigned short*)alloc(4096 * 2);
    unsigned short* wf3 = (unsigned short*)alloc(4096 * 2);
    unsigned short* bufA = (unsigned short*)alloc((size_t)(N + 1) * D * 2);  // + zero row
    unsigned short* hbuf = (unsigned short*)alloc((size_t)N * D * 2);  // bf16 node feats
    float*    outf    = (float*)d_out;  // final fp32 output

    const int AGGB = (N + 3) / 4;           // one wave per node (proven residency)
    const int MMB  = (((N + 15) >> 4) + 3) / 4;  // one 16-row tile per wave

    // ---- bucketed CSR build (once, reused 3x; zero global atomics) ----
    // side jobs folded in: slab-zero + W repack into count; zero-row into fill;
    // basescan deleted (scatter/fill derive bases from btot in-block)
    bucket_count_kernel<<<NBLK, 256, 0, stream>>>(edges, pbh, slabs,
                                                  W1, W2, W3, wf1, wf2, wf3, E, shift);
    colscan_kernel<<<512, 256, 0, stream>>>(pbh, btot);
    bucket_scatter_kernel<<<NBLK, 256, 0, stream>>>(edges, pbh, btot, staging, E, shift);
    bucket_fill_kernel<<<nbuk, 256, 0, stream>>>(staging, btot, offs, dinv, srcs,
                                                 bufA + (size_t)N * D, shift, N, E);

    // ---- layer 1 (x fp32 in; agg fuses BN1 stats) ----
    mm_bn_kernel<<<MMB, 256, 0, stream>>>(x, nullptr, 0, wf1, nullptr, nullptr, nullptr, 0,
                                          inv_n, dinv, bufA, N);
    agg_kernel<<<AGGB, 256, 0, stream>>>(bufA, offs, srcs, dinv, b1, hbuf, nullptr, 1,
                                         slabs, 1, N);

    // ---- layer 2 (hbuf bf16 in; BN1 via slab-reduce in mm; agg fuses BN2 stats) ----
    mm_bn_kernel<<<MMB, 256, 0, stream>>>(nullptr, hbuf, 1, wf2, slabs, gamma1, beta1, 1,
                                          inv_n, dinv, bufA, N);
    agg_kernel<<<AGGB, 256, 0, stream>>>(bufA, offs, srcs, dinv, b2, hbuf, nullptr, 1,
                                         slabs + 16 * 128, 1, N);

    // ---- layer 3 (hbuf bf16 in; BN2 via slab-reduce; fp32 out to d_out) ----
    mm_bn_kernel<<<MMB, 256, 0, stream>>>(nullptr, hbuf, 1, wf3, slabs + 16 * 128,
                                          gamma2, beta2, 1, inv_n, dinv, bufA, N);
    agg_kernel<<<AGGB, 256, 0, stream>>>(bufA, offs, srcs, dinv, b3, nullptr, outf, 0,
                                         nullptr, 0, N);
}